// Round 1
// baseline (1718.309 us; speedup 1.0000x reference)
//
#include <hip/hip_runtime.h>

#define HW 112
#define PP 12544      // HW*HW
#define BB 4
#define RR 49
#define RS 256

typedef __bf16 bf16;
typedef __bf16 bf16x8 __attribute__((ext_vector_type(8)));
typedef float f32x4 __attribute__((ext_vector_type(4)));

// XOR-swizzled byte offset inside a row-major bf16 tile with 128B rows (64 halfs)
__device__ __forceinline__ int swz128(int row, int halfcol) {
  int byte = halfcol * 2;
  return row * 128 + ((((byte >> 4) ^ row) & 7) * 16) + (byte & 15);
}
// same for 512B rows (256 halfs): swizzle within each 128B sub-block
__device__ __forceinline__ int swz512(int row, int halfcol) {
  int byte = halfcol * 2;
  return row * 512 + (byte & ~127) + ((((byte >> 4) ^ row) & 7) * 16) + (byte & 15);
}

__device__ __forceinline__ float gelu_exact(float x) {
  return 0.5f * x * (1.f + erff(x * 0.70710678118654752f));
}

#define FMA16(acc, wv, xv) do { \
  acc[0][0] += wv.x*xv.x; acc[0][1] += wv.x*xv.y; acc[0][2] += wv.x*xv.z; acc[0][3] += wv.x*xv.w; \
  acc[1][0] += wv.y*xv.x; acc[1][1] += wv.y*xv.y; acc[1][2] += wv.y*xv.z; acc[1][3] += wv.y*xv.w; \
  acc[2][0] += wv.z*xv.x; acc[2][1] += wv.z*xv.y; acc[2][2] += wv.z*xv.z; acc[2][3] += wv.z*xv.w; \
  acc[3][0] += wv.w*xv.x; acc[3][1] += wv.w*xv.y; acc[3][2] += wv.w*xv.z; acc[3][3] += wv.w*xv.w; \
} while (0)

// ---------------- prep: bilinear 2x-downsample (== 2x2 avg), concat, region mask ----------------
__global__ __launch_bounds__(256) void k_prep(const float* __restrict__ ex0, const float* __restrict__ ex,
    const float* __restrict__ img, const float* __restrict__ pre,
    float* __restrict__ xcat, float* __restrict__ maskr) {
  int t = blockIdx.x * 256 + threadIdx.x;
  if (t < BB * 131 * PP) {
    int p = t % PP; int nc = t / PP; int c = nc % 131; int n = nc / 131;
    int h = p / HW, w = p % HW;
    float val;
    if (c < 64) {
      const float* s = ex0 + (((size_t)(n * 64 + c)) * 224 + 2 * h) * 224 + 2 * w;
      val = 0.5f * (0.5f * (s[0] + s[224]) + 0.5f * (s[1] + s[225]));
    } else if (c < 128) {
      val = ex[((size_t)(n * 64 + (c - 64))) * PP + p];
    } else {
      const float* s = img + (((size_t)(n * 3 + (c - 128))) * 224 + 2 * h) * 224 + 2 * w;
      val = 0.5f * (0.5f * (s[0] + s[224]) + 0.5f * (s[1] + s[225]));
    }
    xcat[t] = val;
  }
  if (t < BB * PP) {
    int p = t % PP, n = t / PP;
    int h = p / HW, w = p % HW;
    const float* s = pre + ((size_t)n * 224 + 2 * h) * 224 + 2 * w;
    float v = 0.5f * (0.5f * (s[0] + s[224]) + 0.5f * (s[1] + s[225]));
    float mv = (v > 0.0f) ? 0.0f : -100.0f;
    int r = (h >> 4) * 7 + (w >> 4); int sIdx = (h & 15) * 16 + (w & 15);
    maskr[(n * RR + r) * RS + sIdx] = mv;
  }
}

// ---------------- conv0: 3x3, 131->64, SAME ----------------
#define CCH 16
__global__ __launch_bounds__(256) void k_conv0(const float* __restrict__ xc, const float* __restrict__ w,
    const float* __restrict__ bias, float* __restrict__ out) {
  __shared__ float s_in[CCH][6][18];
  __shared__ float s_w[CCH][9][64];
  int n = blockIdx.z;
  int w0 = blockIdx.x * 16, h0 = blockIdx.y * 4;
  int tid = threadIdx.x;
  int to = tid >> 4, tp = tid & 15;
  int prow = tp >> 2, pcol = (tp & 3) * 4;
  float acc[4][4] = {};
  for (int c0 = 0; c0 < 131; c0 += CCH) {
    int cc = min(CCH, 131 - c0);
    for (int i = tid; i < cc * 108; i += 256) {
      int c = i / 108; int rem = i % 108; int rr = rem / 18, cl = rem % 18;
      int gh = h0 + rr - 1, gw = w0 + cl - 1;
      float v = 0.f;
      if ((unsigned)gh < HW && (unsigned)gw < HW)
        v = xc[((size_t)(n * 131 + c0 + c)) * PP + gh * HW + gw];
      s_in[c][rr][cl] = v;
    }
    for (int i = tid; i < cc * 576; i += 256) {
      int c = i / 576; int rem = i % 576; int k = rem >> 6, o = rem & 63;
      s_w[c][k][o] = w[((size_t)(o * 131) + c0 + c) * 9 + k];
    }
    __syncthreads();
    for (int c = 0; c < cc; c++) {
      #pragma unroll
      for (int kh = 0; kh < 3; kh++) {
        #pragma unroll
        for (int kw = 0; kw < 3; kw++) {
          const float4 wv = *(const float4*)&s_w[c][kh * 3 + kw][to * 4];
          const float* xp = &s_in[c][prow + kh][pcol + kw];
          float4 xv; xv.x = xp[0]; xv.y = xp[1]; xv.z = xp[2]; xv.w = xp[3];
          FMA16(acc, wv, xv);
        }
      }
    }
    __syncthreads();
  }
  #pragma unroll
  for (int a = 0; a < 4; a++) {
    int o = to * 4 + a;
    float bi = bias[o];
    size_t base = ((size_t)(n * 64 + o)) * PP + (h0 + prow) * HW + w0 + pcol;
    #pragma unroll
    for (int b2 = 0; b2 < 4; b2++) out[base + b2] = acc[a][b2] + bi;
  }
}

// ---------------- per-pixel LayerNorm over 64 channels ----------------
__global__ __launch_bounds__(256) void k_ln(const float* __restrict__ x, const float* __restrict__ g,
    const float* __restrict__ b, float* __restrict__ y) {
  int t = blockIdx.x * 256 + threadIdx.x;
  if (t >= BB * PP) return;
  int n = t / PP, p = t % PP;
  const float* xp = x + (size_t)n * 64 * PP + p;
  float v[64]; float mu = 0.f;
  #pragma unroll
  for (int c = 0; c < 64; c++) { v[c] = xp[(size_t)c * PP]; mu += v[c]; }
  mu *= (1.f / 64.f);
  float var = 0.f;
  #pragma unroll
  for (int c = 0; c < 64; c++) { float d = v[c] - mu; var += d * d; }
  var *= (1.f / 64.f);
  float rs = rsqrtf(var + 1e-5f);
  float* yp = y + (size_t)n * 64 * PP + p;
  #pragma unroll
  for (int c = 0; c < 64; c++) yp[(size_t)c * PP] = (v[c] - mu) * rs * g[c] + b[c];
}

// ---------------- generic 1x1 conv (GEMM): MODE 0 write, 1 gelu, 2 +=, 3 qkv special ----------------
template <int MODE>
__global__ __launch_bounds__(256) void k_gemm(const float* __restrict__ in, const float* __restrict__ w,
    const float* __restrict__ bias, float* __restrict__ out, int Cin, int nsin, int nsout,
    bf16* __restrict__ qRo, bf16* __restrict__ kRo, bf16* __restrict__ vTo) {
  __shared__ float s_in[64][64];
  __shared__ float s_w[64][68];
  int n = blockIdx.z;
  int p0 = blockIdx.x * 64, o0 = blockIdx.y * 64;
  int tid = threadIdx.x;
  int to = tid >> 4, tp = tid & 15;
  float acc[4][4] = {};
  for (int c0 = 0; c0 < Cin; c0 += 64) {
    for (int it = 0; it < 16; it++) {
      int i = tid + it * 256;
      int c = i >> 6, pp = i & 63;
      s_in[c][pp] = in[(size_t)n * nsin + (size_t)(c0 + c) * PP + p0 + pp];
    }
    for (int it = 0; it < 16; it++) {
      int i = tid + it * 256;
      int c = i & 63, oo = i >> 6;
      s_w[c][oo] = w[(size_t)(o0 + oo) * Cin + c0 + c];
    }
    __syncthreads();
    #pragma unroll 8
    for (int c = 0; c < 64; c++) {
      const float4 xv = *(const float4*)&s_in[c][tp * 4];
      const float4 wv = *(const float4*)&s_w[c][to * 4];
      FMA16(acc, wv, xv);
    }
    __syncthreads();
  }
  int p = p0 + tp * 4;
  #pragma unroll
  for (int a = 0; a < 4; a++) {
    int o = o0 + to * 4 + a;
    float bi = bias[o];
    size_t base = (size_t)n * nsout + (size_t)o * PP + p;
    #pragma unroll
    for (int b2 = 0; b2 < 4; b2++) {
      float rv = acc[a][b2] + bi;
      if (MODE == 0) out[base + b2] = rv;
      else if (MODE == 1) out[base + b2] = gelu_exact(rv);
      else if (MODE == 2) out[base + b2] += rv;
      else {
        out[base + b2] = rv;
        int p2 = p + b2; int h = p2 / HW, ww2 = p2 % HW;
        int r = (h >> 4) * 7 + (ww2 >> 4), s = (h & 15) * 16 + (ww2 & 15);
        int cch = o & 63;
        if (o0 == 0)       qRo[(((size_t)n * RR + r) * RS + s) * 64 + cch] = (bf16)(rv * 0.125f);
        else if (o0 == 64) kRo[(((size_t)n * RR + r) * RS + s) * 64 + cch] = (bf16)rv;
        else               vTo[(((size_t)n * RR + r) * 64 + cch) * RS + s] = (bf16)rv;
      }
    }
  }
}

// ---------------- region means qd/kd ----------------
__global__ __launch_bounds__(256) void k_qdkd(const float* __restrict__ qkv, float* __restrict__ qd,
    float* __restrict__ kd) {
  int t = blockIdx.x * 256 + threadIdx.x;
  if (t >= 2 * BB * 64 * RR) return;
  int sel = t / (BB * 64 * RR); int rem = t % (BB * 64 * RR);
  int r = rem % RR; int c = (rem / RR) & 63; int n = rem / (RR * 64);
  const float* src = qkv + (size_t)n * 192 * PP + (size_t)(sel * 64 + c) * PP;
  int wh = r / 7, ww = r % 7;
  float s = 0.f;
  for (int lh = 0; lh < 16; lh++) {
    const float* row = src + (wh * 16 + lh) * HW + ww * 16;
    #pragma unroll
    for (int lw = 0; lw < 16; lw++) s += row[lw];
  }
  (sel ? kd : qd)[(n * 64 + c) * RR + r] = s * (1.f / 256.f);
}

// ---------------- region affinity + top-4 ----------------
__global__ void k_topk(const float* __restrict__ qd, const float* __restrict__ kd, int* __restrict__ gidx) {
  int n = blockIdx.x; int pq = threadIdx.x;
  if (pq >= RR) return;
  float a[RR];
  #pragma unroll
  for (int j = 0; j < RR; j++) a[j] = 0.f;
  for (int c = 0; c < 64; c++) {
    float qv = qd[(n * 64 + c) * RR + pq];
    #pragma unroll
    for (int j = 0; j < RR; j++) a[j] += qv * kd[(n * 64 + c) * RR + j];
  }
  for (int t = 0; t < 4; t++) {
    int best = 0; float bv = -3e38f;
    #pragma unroll
    for (int j = 0; j < RR; j++) { if (a[j] > bv) { bv = a[j]; best = j; } }
    gidx[(n * RR + pq) * 4 + t] = best;
    #pragma unroll
    for (int j = 0; j < RR; j++) { if (j == best) a[j] = -3e38f; }
  }
}

// ---------------- gathered-region flash attention (bf16 MFMA) ----------------
__global__ __launch_bounds__(256) void k_attn(const bf16* __restrict__ qR, const bf16* __restrict__ kR,
    const bf16* __restrict__ vT, const float* __restrict__ maskr, const int* __restrict__ gidx,
    float* __restrict__ attnR) {
  __shared__ bf16 sQ[256 * 64];
  __shared__ bf16 sK[256 * 64];
  __shared__ bf16 sV[64 * 256];
  __shared__ bf16 sP[4][64 * 64];
  __shared__ float sMask[256];
  int nb = blockIdx.x; int n = nb / RR, r = nb % RR;
  int tid = threadIdx.x, lane = tid & 63, wv = tid >> 6;
  int lo = lane & 15, hi = lane >> 4;
  int m0 = wv * 64;

  { // stage Q (swizzled)
    const bf16* src = qR + ((size_t)(n * RR + r)) * RS * 64;
    for (int g = tid; g < 2048; g += 256) {
      int row = g >> 3, c4 = g & 7;
      uint4 d = *(const uint4*)(src + row * 64 + c4 * 8);
      *(uint4*)((char*)sQ + row * 128 + (((c4 ^ row) & 7) * 16)) = d;
    }
  }

  f32x4 zero4 = {0.f, 0.f, 0.f, 0.f};
  f32x4 Oacc[4][4];
  #pragma unroll
  for (int mi = 0; mi < 4; mi++)
    #pragma unroll
    for (int di = 0; di < 4; di++) Oacc[mi][di] = zero4;
  float mrun[16], lrun[16];
  #pragma unroll
  for (int s = 0; s < 16; s++) { mrun[s] = -3e38f; lrun[s] = 0.f; }

  for (int t = 0; t < 4; t++) {
    int j = gidx[(n * RR + r) * 4 + t];
    __syncthreads();  // Q staged (t=0) / prev tile compute done (t>0)
    const bf16* ksrc = kR + ((size_t)(n * RR + j)) * RS * 64;
    for (int g = tid; g < 2048; g += 256) {
      int row = g >> 3, c4 = g & 7;
      uint4 d = *(const uint4*)(ksrc + row * 64 + c4 * 8);
      *(uint4*)((char*)sK + row * 128 + (((c4 ^ row) & 7) * 16)) = d;
    }
    const bf16* vsrc = vT + ((size_t)(n * RR + j)) * 64 * RS;
    for (int g = tid; g < 2048; g += 256) {
      int row = g >> 5, c32 = g & 31;
      uint4 d = *(const uint4*)(vsrc + row * 256 + c32 * 8);
      *(uint4*)((char*)sV + row * 512 + (c32 & 24) * 16 + (((c32 ^ row) & 7) * 16)) = d;
    }
    sMask[tid] = maskr[(n * RR + j) * RS + tid];
    __syncthreads();

    for (int sub = 0; sub < 4; sub++) {
      f32x4 Sacc[4][4];
      #pragma unroll
      for (int mi = 0; mi < 4; mi++)
        #pragma unroll
        for (int ni = 0; ni < 4; ni++) Sacc[mi][ni] = zero4;
      #pragma unroll
      for (int kk = 0; kk < 2; kk++) {
        bf16x8 aF[4];
        #pragma unroll
        for (int mi = 0; mi < 4; mi++)
          aF[mi] = *(const bf16x8*)((const char*)sQ + swz128(m0 + mi * 16 + lo, kk * 32 + hi * 8));
        #pragma unroll
        for (int ni = 0; ni < 4; ni++) {
          bf16x8 bF = *(const bf16x8*)((const char*)sK + swz128(sub * 64 + ni * 16 + lo, kk * 32 + hi * 8));
          #pragma unroll
          for (int mi = 0; mi < 4; mi++)
            Sacc[mi][ni] = __builtin_amdgcn_mfma_f32_16x16x32_bf16(aF[mi], bF, Sacc[mi][ni], 0, 0, 0);
        }
      }
      // online softmax update
      float mv[4];
      #pragma unroll
      for (int ni = 0; ni < 4; ni++) mv[ni] = sMask[sub * 64 + ni * 16 + lo];
      bf16* sPw = sP[wv];
      #pragma unroll
      for (int mi = 0; mi < 4; mi++) {
        #pragma unroll
        for (int jj = 0; jj < 4; jj++) {
          int slot = mi * 4 + jj;
          float cm = fmaxf(fmaxf(Sacc[mi][0][jj] + mv[0], Sacc[mi][1][jj] + mv[1]),
                           fmaxf(Sacc[mi][2][jj] + mv[2], Sacc[mi][3][jj] + mv[3]));
          #pragma unroll
          for (int d2 = 1; d2 < 16; d2 <<= 1) cm = fmaxf(cm, __shfl_xor(cm, d2, 64));
          float nm = fmaxf(mrun[slot], cm);
          float sc = __expf(mrun[slot] - nm);
          float rs = 0.f; float pv[4];
          #pragma unroll
          for (int ni = 0; ni < 4; ni++) { pv[ni] = __expf(Sacc[mi][ni][jj] + mv[ni] - nm); rs += pv[ni]; }
          #pragma unroll
          for (int d2 = 1; d2 < 16; d2 <<= 1) rs += __shfl_xor(rs, d2, 64);
          mrun[slot] = nm; lrun[slot] = lrun[slot] * sc + rs;
          #pragma unroll
          for (int di = 0; di < 4; di++) Oacc[mi][di][jj] *= sc;
          int prow = mi * 16 + hi * 4 + jj;
          #pragma unroll
          for (int ni = 0; ni < 4; ni++)
            *(bf16*)((char*)sPw + swz128(prow, ni * 16 + lo)) = (bf16)pv[ni];
        }
      }
      // PV
      #pragma unroll
      for (int kk = 0; kk < 2; kk++) {
        bf16x8 pF[4];
        #pragma unroll
        for (int mi = 0; mi < 4; mi++)
          pF[mi] = *(const bf16x8*)((const char*)sPw + swz128(mi * 16 + lo, kk * 32 + hi * 8));
        #pragma unroll
        for (int di = 0; di < 4; di++) {
          bf16x8 vF = *(const bf16x8*)((const char*)sV + swz512(di * 16 + lo, sub * 64 + kk * 32 + hi * 8));
          #pragma unroll
          for (int mi = 0; mi < 4; mi++)
            Oacc[mi][di] = __builtin_amdgcn_mfma_f32_16x16x32_bf16(pF[mi], vF, Oacc[mi][di], 0, 0, 0);
        }
      }
    }
  }
  float* dst = attnR + ((size_t)(n * RR + r)) * RS * 64;
  #pragma unroll
  for (int mi = 0; mi < 4; mi++) {
    #pragma unroll
    for (int jj = 0; jj < 4; jj++) {
      float inv = 1.f / lrun[mi * 4 + jj];
      int row = m0 + mi * 16 + hi * 4 + jj;
      #pragma unroll
      for (int di = 0; di < 4; di++)
        dst[row * 64 + di * 16 + lo] = Oacc[mi][di][jj] * inv;
    }
  }
}

// ---------------- lepe 5x5 depthwise + from_regions ----------------
__global__ __launch_bounds__(256) void k_lepe(const float* __restrict__ attnR, const float* __restrict__ qkv,
    const float* __restrict__ lw, const float* __restrict__ lb, float* __restrict__ z) {
  int t = blockIdx.x * 256 + threadIdx.x;
  if (t >= BB * 64 * PP) return;
  int p = t % PP; int c = (t / PP) & 63; int n = t / (64 * PP);
  int h = p / HW, w = p % HW;
  const float* vsp = qkv + (size_t)n * 192 * PP + (size_t)(128 + c) * PP;
  float acc = lb[c];
  const float* wc = lw + c * 25;
  #pragma unroll
  for (int dh = 0; dh < 5; dh++) {
    int hh = h + dh - 2; if ((unsigned)hh >= HW) continue;
    #pragma unroll
    for (int dw = 0; dw < 5; dw++) {
      int ww2 = w + dw - 2; if ((unsigned)ww2 >= HW) continue;
      acc += vsp[hh * HW + ww2] * wc[dh * 5 + dw];
    }
  }
  int r = (h >> 4) * 7 + (w >> 4); int s = (h & 15) * 16 + (w & 15);
  z[t] = acc + attnR[(((size_t)n * RR + r) * RS + s) * 64 + c];
}

extern "C" void kernel_launch(void* const* d_in, const int* in_sizes, int n_in,
                              void* d_out, int out_size, void* d_ws, size_t ws_size,
                              hipStream_t stream) {
  const float* ex0 = (const float*)d_in[0];
  const float* ex  = (const float*)d_in[1];
  const float* img = (const float*)d_in[2];
  const float* pre = (const float*)d_in[3];
  const float* c0w = (const float*)d_in[4];
  const float* c0b = (const float*)d_in[5];
  const float* ln1g = (const float*)d_in[6];
  const float* ln1b = (const float*)d_in[7];
  const float* ln2g = (const float*)d_in[8];
  const float* ln2b = (const float*)d_in[9];
  const float* qkvw = (const float*)d_in[10];
  const float* qkvb = (const float*)d_in[11];
  const float* lw = (const float*)d_in[12];
  const float* lb = (const float*)d_in[13];
  const float* pw = (const float*)d_in[14];
  const float* pb = (const float*)d_in[15];
  const float* f1w = (const float*)d_in[16];
  const float* f1b = (const float*)d_in[17];
  const float* f2w = (const float*)d_in[18];
  const float* f2b = (const float*)d_in[19];

  float* x = (float*)d_out;   // residual stream lives in d_out
  float* W = (float*)d_ws;
  size_t o = 0;
  float* bigA = W;             o += 12845056;  // xcat (6.57M) / hbuf (12.85M) overlay
  float* y    = W + o;         o += 3211264;   // LN out; also attnR overlay
  float* qkv  = W + o;         o += 9633792;
  float* z    = W + o;         o += 3211264;
  bf16* qR = (bf16*)(W + o);   o += 1605632;
  bf16* kR = (bf16*)(W + o);   o += 1605632;
  bf16* vT = (bf16*)(W + o);   o += 1605632;
  float* qd = W + o;           o += 12544;
  float* kd = W + o;           o += 12544;
  float* maskr = W + o;        o += 50176;
  int* gidx = (int*)(W + o);   o += 784;
  float* xcat = bigA;
  float* hbuf = bigA;
  float* attnR = y;

  k_prep<<<dim3((BB * 131 * PP + 255) / 256), dim3(256), 0, stream>>>(ex0, ex, img, pre, xcat, maskr);
  k_conv0<<<dim3(7, 28, BB), dim3(256), 0, stream>>>(xcat, c0w, c0b, x);
  for (int i = 0; i < 4; i++) {
    k_ln<<<dim3((BB * PP + 255) / 256), dim3(256), 0, stream>>>(x, ln1g + i * 64, ln1b + i * 64, y);
    k_gemm<3><<<dim3(196, 3, BB), dim3(256), 0, stream>>>(y, qkvw + (size_t)i * 192 * 64, qkvb + i * 192,
        qkv, 64, 64 * PP, 192 * PP, qR, kR, vT);
    k_qdkd<<<dim3((2 * BB * 64 * RR + 255) / 256), dim3(256), 0, stream>>>(qkv, qd, kd);
    k_topk<<<dim3(BB), dim3(64), 0, stream>>>(qd, kd, gidx);
    k_attn<<<dim3(BB * RR), dim3(256), 0, stream>>>(qR, kR, vT, maskr, gidx, attnR);
    k_lepe<<<dim3((BB * 64 * PP + 255) / 256), dim3(256), 0, stream>>>(attnR, qkv,
        lw + (size_t)i * 64 * 25, lb + i * 64, z);
    k_gemm<2><<<dim3(196, 1, BB), dim3(256), 0, stream>>>(z, pw + (size_t)i * 64 * 64, pb + i * 64,
        x, 64, 64 * PP, 64 * PP, nullptr, nullptr, nullptr);
    k_ln<<<dim3((BB * PP + 255) / 256), dim3(256), 0, stream>>>(x, ln2g + i * 64, ln2b + i * 64, y);
    k_gemm<1><<<dim3(196, 4, BB), dim3(256), 0, stream>>>(y, f1w + (size_t)i * 256 * 64, f1b + i * 256,
        hbuf, 64, 64 * PP, 256 * PP, nullptr, nullptr, nullptr);
    k_gemm<2><<<dim3(196, 1, BB), dim3(256), 0, stream>>>(hbuf, f2w + (size_t)i * 64 * 256, f2b + i * 64,
        x, 256, 256 * PP, 64 * PP, nullptr, nullptr, nullptr);
  }
}

// Round 2
// 1096.749 us; speedup vs baseline: 1.5667x; 1.5667x over previous
//
#include <hip/hip_runtime.h>

#define HW 112
#define PP 12544
#define BB 4
#define RR 49
#define RS 256

typedef __bf16 bf16;
typedef __bf16 bf16x8 __attribute__((ext_vector_type(8)));
typedef __bf16 bf16x4 __attribute__((ext_vector_type(4)));
typedef float f32x4 __attribute__((ext_vector_type(4)));

__device__ __forceinline__ int swz128(int row, int halfcol) {
  int byte = halfcol * 2;
  return row * 128 + ((((byte >> 4) ^ row) & 7) * 16) + (byte & 15);
}
__device__ __forceinline__ int swz512(int row, int halfcol) {
  int byte = halfcol * 2;
  return row * 512 + (byte & ~127) + ((((byte >> 4) ^ row) & 7) * 16) + (byte & 15);
}

__device__ __forceinline__ float gelu_exact(float x) {
  return 0.5f * x * (1.f + erff(x * 0.70710678118654752f));
}

#define FMA16(acc, wv, xv) do { \
  acc[0][0] += wv.x*xv.x; acc[0][1] += wv.x*xv.y; acc[0][2] += wv.x*xv.z; acc[0][3] += wv.x*xv.w; \
  acc[1][0] += wv.y*xv.x; acc[1][1] += wv.y*xv.y; acc[1][2] += wv.y*xv.z; acc[1][3] += wv.y*xv.w; \
  acc[2][0] += wv.z*xv.x; acc[2][1] += wv.z*xv.y; acc[2][2] += wv.z*xv.z; acc[2][3] += wv.z*xv.w; \
  acc[3][0] += wv.w*xv.x; acc[3][1] += wv.w*xv.y; acc[3][2] += wv.w*xv.z; acc[3][3] += wv.w*xv.w; \
} while (0)

// ---------------- prep: bilinear 2x down (=2x2 avg), concat, region mask ----------------
__global__ __launch_bounds__(256) void k_prep(const float* __restrict__ ex0, const float* __restrict__ ex,
    const float* __restrict__ img, const float* __restrict__ pre,
    float* __restrict__ xcat, float* __restrict__ maskr) {
  int t = blockIdx.x * 256 + threadIdx.x;
  if (t < BB * 131 * PP) {
    int p = t % PP; int nc = t / PP; int c = nc % 131; int n = nc / 131;
    int h = p / HW, w = p % HW;
    float val;
    if (c < 64) {
      const float* s = ex0 + (((size_t)(n * 64 + c)) * 224 + 2 * h) * 224 + 2 * w;
      val = 0.5f * (0.5f * (s[0] + s[224]) + 0.5f * (s[1] + s[225]));
    } else if (c < 128) {
      val = ex[((size_t)(n * 64 + (c - 64))) * PP + p];
    } else {
      const float* s = img + (((size_t)(n * 3 + (c - 128))) * 224 + 2 * h) * 224 + 2 * w;
      val = 0.5f * (0.5f * (s[0] + s[224]) + 0.5f * (s[1] + s[225]));
    }
    xcat[t] = val;
  }
  if (t < BB * PP) {
    int p = t % PP, n = t / PP;
    int h = p / HW, w = p % HW;
    const float* s = pre + ((size_t)n * 224 + 2 * h) * 224 + 2 * w;
    float v = 0.5f * (0.5f * (s[0] + s[224]) + 0.5f * (s[1] + s[225]));
    float mv = (v > 0.0f) ? 0.0f : -100.0f;
    int r = (h >> 4) * 7 + (w >> 4); int sIdx = (h & 15) * 16 + (w & 15);
    maskr[(n * RR + r) * RS + sIdx] = mv;
  }
}

// ---------------- conv0 weight pre-transpose: w[o][c][k] -> wT[c][k][o] ----------------
__global__ __launch_bounds__(256) void k_wt(const float* __restrict__ w, float* __restrict__ wT) {
  int t = blockIdx.x * 256 + threadIdx.x;
  if (t >= 131 * 9 * 64) return;
  int o = t & 63; int k = (t >> 6) % 9; int c = t / 576;
  wT[t] = w[((size_t)(o * 131) + c) * 9 + k];
}

// ---------------- conv0 v2: 3x3, 131->64, coalesced wT staging + reg sliding window ----------------
#define CC2 8
__global__ __launch_bounds__(256) void k_conv0(const float* __restrict__ xc, const float* __restrict__ wT,
    const float* __restrict__ bias, float* __restrict__ out_t) {
  __shared__ float s_in[CC2][6][20];
  __shared__ float s_w[CC2][9][64];
  int n = blockIdx.z;
  int w0 = blockIdx.x * 16, h0 = blockIdx.y * 4;
  int tid = threadIdx.x;
  int to = tid >> 4, tp = tid & 15;
  int prow = tp >> 2, pcol = (tp & 3) * 4;
  float acc[4][4] = {};
  for (int c0 = 0; c0 < 131; c0 += CC2) {
    int cc = min(CC2, 131 - c0);
    for (int i = tid; i < cc * 108; i += 256) {
      int c = i / 108; int rem = i % 108; int rr = rem / 18, cl = rem % 18;
      int gh = h0 + rr - 1, gw = w0 + cl - 1;
      float v = 0.f;
      if ((unsigned)gh < HW && (unsigned)gw < HW)
        v = xc[((size_t)(n * 131 + c0 + c)) * PP + gh * HW + gw];
      s_in[c][rr][cl] = v;
    }
    for (int i = tid; i < cc * 144; i += 256) {
      int c = i / 144; int rem = i % 144; int k = rem >> 4, q = rem & 15;
      *(float4*)&s_w[c][k][q * 4] = *(const float4*)&wT[((size_t)(c0 + c)) * 576 + k * 64 + q * 4];
    }
    __syncthreads();
    for (int c = 0; c < cc; c++) {
      #pragma unroll
      for (int kh = 0; kh < 3; kh++) {
        float4 x0 = *(const float4*)&s_in[c][prow + kh][pcol];
        float4 x1 = *(const float4*)&s_in[c][prow + kh][pcol + 4];
        float4 xv;
        {
          const float4 wv = *(const float4*)&s_w[c][kh * 3][to * 4];
          FMA16(acc, wv, x0);
        }
        {
          const float4 wv = *(const float4*)&s_w[c][kh * 3 + 1][to * 4];
          xv.x = x0.y; xv.y = x0.z; xv.z = x0.w; xv.w = x1.x;
          FMA16(acc, wv, xv);
        }
        {
          const float4 wv = *(const float4*)&s_w[c][kh * 3 + 2][to * 4];
          xv.x = x0.z; xv.y = x0.w; xv.z = x1.x; xv.w = x1.y;
          FMA16(acc, wv, xv);
        }
      }
    }
    __syncthreads();
  }
  float4 bi = *(const float4*)&bias[to * 4];
  #pragma unroll
  for (int b2 = 0; b2 < 4; b2++) {
    int p = (h0 + prow) * HW + w0 + pcol + b2;
    float4 st;
    st.x = acc[0][b2] + bi.x; st.y = acc[1][b2] + bi.y;
    st.z = acc[2][b2] + bi.z; st.w = acc[3][b2] + bi.w;
    *(float4*)&out_t[((size_t)n * PP + p) * 64 + to * 4] = st;
  }
}

// ---------------- LayerNorm (transposed layout): x_t[p][64] f32 -> y_t[p][64] bf16 ----------------
__global__ __launch_bounds__(256) void k_lnT(const float* __restrict__ x, const float* __restrict__ g,
    const float* __restrict__ b, bf16* __restrict__ y) {
  int t = blockIdx.x * 256 + threadIdx.x;
  if (t >= BB * PP) return;
  const float* xp = x + (size_t)t * 64;
  float v[64]; float mu = 0.f;
  #pragma unroll
  for (int i = 0; i < 16; i++) {
    float4 d = *(const float4*)&xp[i * 4];
    v[i * 4] = d.x; v[i * 4 + 1] = d.y; v[i * 4 + 2] = d.z; v[i * 4 + 3] = d.w;
    mu += d.x + d.y + d.z + d.w;
  }
  mu *= (1.f / 64.f);
  float var = 0.f;
  #pragma unroll
  for (int c = 0; c < 64; c++) { float d = v[c] - mu; var += d * d; }
  var *= (1.f / 64.f);
  float rs = rsqrtf(var + 1e-5f);
  bf16* yp = y + (size_t)t * 64;
  #pragma unroll
  for (int i = 0; i < 8; i++) {
    bf16x8 o8;
    #pragma unroll
    for (int j = 0; j < 8; j++) {
      int c = i * 8 + j;
      o8[j] = (bf16)((v[c] - mu) * rs * g[c] + b[c]);
    }
    *(bf16x8*)(yp + i * 8) = o8;
  }
}

// ---------------- MFMA GEMM over transposed activations ----------------
// A: bf16 [p][Cin] rows; B: f32 weights [Nout][Cin]; D[m=p][n=o]
// MODE 0: qkv (blockIdx.y selects q/k/v epilogue), 1: gelu->h_t bf16 (ld 256), 2: += into x_t f32
template <int MODE>
__global__ __launch_bounds__(256) void k_mgemm(const bf16* __restrict__ A, const float* __restrict__ w,
    const float* __restrict__ bias, int Cin, float* __restrict__ xo, bf16* __restrict__ ho,
    bf16* __restrict__ qRo, bf16* __restrict__ kRo, bf16* __restrict__ vTo, bf16* __restrict__ vto) {
  __shared__ bf16 sA[128 * 64];
  __shared__ bf16 sB[64 * 64];
  int n = blockIdx.z;
  int p0 = blockIdx.x * 128, o0 = blockIdx.y * 64;
  int tid = threadIdx.x; int wv = tid >> 6; int lane = tid & 63;
  int lo = lane & 15, hi = lane >> 4;
  f32x4 acc[2][4];
  #pragma unroll
  for (int mi = 0; mi < 2; mi++)
    #pragma unroll
    for (int ni = 0; ni < 4; ni++) acc[mi][ni] = (f32x4){0.f, 0.f, 0.f, 0.f};
  const bf16* Abase = A + (size_t)n * PP * Cin;
  for (int c0 = 0; c0 < Cin; c0 += 64) {
    #pragma unroll
    for (int it = 0; it < 4; it++) {
      int gidx2 = tid + it * 256;
      int row = gidx2 >> 3, c4 = gidx2 & 7;
      uint4 d = *(const uint4*)(Abase + (size_t)(p0 + row) * Cin + c0 + c4 * 8);
      *(uint4*)((char*)sA + row * 128 + (((c4 ^ row) & 7) * 16)) = d;
    }
    #pragma unroll
    for (int it = 0; it < 4; it++) {
      int gidx2 = tid + it * 256;
      int oo = gidx2 >> 4, q = gidx2 & 15;
      float4 wv4 = *(const float4*)&w[(size_t)(o0 + oo) * Cin + c0 + q * 4];
      bf16x4 b4; b4[0] = (bf16)wv4.x; b4[1] = (bf16)wv4.y; b4[2] = (bf16)wv4.z; b4[3] = (bf16)wv4.w;
      *(bf16x4*)((char*)sB + swz128(oo, q * 4)) = b4;
    }
    __syncthreads();
    #pragma unroll
    for (int kk = 0; kk < 2; kk++) {
      bf16x8 aF[2], bF[4];
      #pragma unroll
      for (int mi = 0; mi < 2; mi++)
        aF[mi] = *(const bf16x8*)((const char*)sA + swz128(wv * 32 + mi * 16 + lo, kk * 32 + hi * 8));
      #pragma unroll
      for (int ni = 0; ni < 4; ni++)
        bF[ni] = *(const bf16x8*)((const char*)sB + swz128(ni * 16 + lo, kk * 32 + hi * 8));
      #pragma unroll
      for (int mi = 0; mi < 2; mi++)
        #pragma unroll
        for (int ni = 0; ni < 4; ni++)
          acc[mi][ni] = __builtin_amdgcn_mfma_f32_16x16x32_bf16(aF[mi], bF[ni], acc[mi][ni], 0, 0, 0);
    }
    __syncthreads();
  }
  float bv[4];
  #pragma unroll
  for (int ni = 0; ni < 4; ni++) bv[ni] = bias[o0 + ni * 16 + lo];
  #pragma unroll
  for (int mi = 0; mi < 2; mi++) {
    #pragma unroll
    for (int r = 0; r < 4; r++) {
      int p = p0 + wv * 32 + mi * 16 + hi * 4 + r;
      int h = p / HW, w2 = p % HW;
      int rg = (h >> 4) * 7 + (w2 >> 4), s = (h & 15) * 16 + (w2 & 15);
      #pragma unroll
      for (int ni = 0; ni < 4; ni++) {
        float rv = acc[mi][ni][r] + bv[ni];
        int o = o0 + ni * 16 + lo;
        if (MODE == 0) {
          int cch = o & 63;
          size_t ridx = ((size_t)(n * RR + rg)) * RS + s;
          if (o0 == 0)       qRo[ridx * 64 + cch] = (bf16)(rv * 0.125f);
          else if (o0 == 64) kRo[ridx * 64 + cch] = (bf16)rv;
          else {
            vTo[(((size_t)(n * RR + rg)) * 64 + cch) * RS + s] = (bf16)rv;
            vto[((size_t)n * PP + p) * 64 + cch] = (bf16)rv;
          }
        } else if (MODE == 1) {
          ho[((size_t)n * PP + p) * 256 + o] = (bf16)gelu_exact(rv);
        } else {
          xo[((size_t)n * PP + p) * 64 + o] += rv;
        }
      }
    }
  }
}

// ---------------- qd/kd from bf16 region buffers ----------------
__global__ __launch_bounds__(256) void k_qdkd2(const bf16* __restrict__ qR, const bf16* __restrict__ kR,
    float* __restrict__ qd, float* __restrict__ kd) {
  int nr = blockIdx.x; int n = nr / RR, r = nr % RR;
  int tid = threadIdx.x;
  int c = tid & 63, sq = tid >> 6;
  const bf16* qb = qR + (size_t)nr * RS * 64;
  const bf16* kb = kR + (size_t)nr * RS * 64;
  float aq = 0.f, ak = 0.f;
  for (int s = sq * 64; s < sq * 64 + 64; s++) {
    aq += (float)qb[s * 64 + c];
    ak += (float)kb[s * 64 + c];
  }
  __shared__ float rq[4][64], rk[4][64];
  rq[sq][c] = aq; rk[sq][c] = ak;
  __syncthreads();
  if (tid < 64) {
    float a = (rq[0][c] + rq[1][c]) + (rq[2][c] + rq[3][c]);
    float k2 = (rk[0][c] + rk[1][c]) + (rk[2][c] + rk[3][c]);
    qd[(n * 64 + c) * RR + r] = a * (1.f / 256.f);
    kd[(n * 64 + c) * RR + r] = k2 * (1.f / 256.f);
  }
}

// ---------------- region affinity + top-4 ----------------
__global__ void k_topk(const float* __restrict__ qd, const float* __restrict__ kd, int* __restrict__ gidx) {
  int n = blockIdx.x; int pq = threadIdx.x;
  if (pq >= RR) return;
  float a[RR];
  #pragma unroll
  for (int j = 0; j < RR; j++) a[j] = 0.f;
  for (int c = 0; c < 64; c++) {
    float qv = qd[(n * 64 + c) * RR + pq];
    #pragma unroll
    for (int j = 0; j < RR; j++) a[j] += qv * kd[(n * 64 + c) * RR + j];
  }
  for (int t = 0; t < 4; t++) {
    int best = 0; float bv = -3e38f;
    #pragma unroll
    for (int j = 0; j < RR; j++) { if (a[j] > bv) { bv = a[j]; best = j; } }
    gidx[(n * RR + pq) * 4 + t] = best;
    #pragma unroll
    for (int j = 0; j < RR; j++) { if (j == best) a[j] = -3e38f; }
  }
}

// ---------------- gathered-region flash attention (bf16 MFMA) — unchanged ----------------
__global__ __launch_bounds__(256) void k_attn(const bf16* __restrict__ qR, const bf16* __restrict__ kR,
    const bf16* __restrict__ vT, const float* __restrict__ maskr, const int* __restrict__ gidx,
    float* __restrict__ attnR) {
  __shared__ bf16 sQ[256 * 64];
  __shared__ bf16 sK[256 * 64];
  __shared__ bf16 sV[64 * 256];
  __shared__ bf16 sP[4][64 * 64];
  __shared__ float sMask[256];
  int nb = blockIdx.x; int n = nb / RR, r = nb % RR;
  int tid = threadIdx.x, lane = tid & 63, wv = tid >> 6;
  int lo = lane & 15, hi = lane >> 4;
  int m0 = wv * 64;

  {
    const bf16* src = qR + ((size_t)(n * RR + r)) * RS * 64;
    for (int g = tid; g < 2048; g += 256) {
      int row = g >> 3, c4 = g & 7;
      uint4 d = *(const uint4*)(src + row * 64 + c4 * 8);
      *(uint4*)((char*)sQ + row * 128 + (((c4 ^ row) & 7) * 16)) = d;
    }
  }

  f32x4 zero4 = {0.f, 0.f, 0.f, 0.f};
  f32x4 Oacc[4][4];
  #pragma unroll
  for (int mi = 0; mi < 4; mi++)
    #pragma unroll
    for (int di = 0; di < 4; di++) Oacc[mi][di] = zero4;
  float mrun[16], lrun[16];
  #pragma unroll
  for (int s = 0; s < 16; s++) { mrun[s] = -3e38f; lrun[s] = 0.f; }

  for (int t = 0; t < 4; t++) {
    int j = gidx[(n * RR + r) * 4 + t];
    __syncthreads();
    const bf16* ksrc = kR + ((size_t)(n * RR + j)) * RS * 64;
    for (int g = tid; g < 2048; g += 256) {
      int row = g >> 3, c4 = g & 7;
      uint4 d = *(const uint4*)(ksrc + row * 64 + c4 * 8);
      *(uint4*)((char*)sK + row * 128 + (((c4 ^ row) & 7) * 16)) = d;
    }
    const bf16* vsrc = vT + ((size_t)(n * RR + j)) * 64 * RS;
    for (int g = tid; g < 2048; g += 256) {
      int row = g >> 5, c32 = g & 31;
      uint4 d = *(const uint4*)(vsrc + row * 256 + c32 * 8);
      *(uint4*)((char*)sV + row * 512 + (c32 & 24) * 16 + (((c32 ^ row) & 7) * 16)) = d;
    }
    sMask[tid] = maskr[(n * RR + j) * RS + tid];
    __syncthreads();

    for (int sub = 0; sub < 4; sub++) {
      f32x4 Sacc[4][4];
      #pragma unroll
      for (int mi = 0; mi < 4; mi++)
        #pragma unroll
        for (int ni = 0; ni < 4; ni++) Sacc[mi][ni] = zero4;
      #pragma unroll
      for (int kk = 0; kk < 2; kk++) {
        bf16x8 aF[4];
        #pragma unroll
        for (int mi = 0; mi < 4; mi++)
          aF[mi] = *(const bf16x8*)((const char*)sQ + swz128(m0 + mi * 16 + lo, kk * 32 + hi * 8));
        #pragma unroll
        for (int ni = 0; ni < 4; ni++) {
          bf16x8 bF = *(const bf16x8*)((const char*)sK + swz128(sub * 64 + ni * 16 + lo, kk * 32 + hi * 8));
          #pragma unroll
          for (int mi = 0; mi < 4; mi++)
            Sacc[mi][ni] = __builtin_amdgcn_mfma_f32_16x16x32_bf16(aF[mi], bF, Sacc[mi][ni], 0, 0, 0);
        }
      }
      float mv[4];
      #pragma unroll
      for (int ni = 0; ni < 4; ni++) mv[ni] = sMask[sub * 64 + ni * 16 + lo];
      bf16* sPw = sP[wv];
      #pragma unroll
      for (int mi = 0; mi < 4; mi++) {
        #pragma unroll
        for (int jj = 0; jj < 4; jj++) {
          int slot = mi * 4 + jj;
          float cm = fmaxf(fmaxf(Sacc[mi][0][jj] + mv[0], Sacc[mi][1][jj] + mv[1]),
                           fmaxf(Sacc[mi][2][jj] + mv[2], Sacc[mi][3][jj] + mv[3]));
          #pragma unroll
          for (int d2 = 1; d2 < 16; d2 <<= 1) cm = fmaxf(cm, __shfl_xor(cm, d2, 64));
          float nm = fmaxf(mrun[slot], cm);
          float sc = __expf(mrun[slot] - nm);
          float rs = 0.f; float pv[4];
          #pragma unroll
          for (int ni = 0; ni < 4; ni++) { pv[ni] = __expf(Sacc[mi][ni][jj] + mv[ni] - nm); rs += pv[ni]; }
          #pragma unroll
          for (int d2 = 1; d2 < 16; d2 <<= 1) rs += __shfl_xor(rs, d2, 64);
          mrun[slot] = nm; lrun[slot] = lrun[slot] * sc + rs;
          #pragma unroll
          for (int di = 0; di < 4; di++) Oacc[mi][di][jj] *= sc;
          int prow = mi * 16 + hi * 4 + jj;
          #pragma unroll
          for (int ni = 0; ni < 4; ni++)
            *(bf16*)((char*)sPw + swz128(prow, ni * 16 + lo)) = (bf16)pv[ni];
        }
      }
      #pragma unroll
      for (int kk = 0; kk < 2; kk++) {
        bf16x8 pF[4];
        #pragma unroll
        for (int mi = 0; mi < 4; mi++)
          pF[mi] = *(const bf16x8*)((const char*)sPw + swz128(mi * 16 + lo, kk * 32 + hi * 8));
        #pragma unroll
        for (int di = 0; di < 4; di++) {
          bf16x8 vF = *(const bf16x8*)((const char*)sV + swz512(di * 16 + lo, sub * 64 + kk * 32 + hi * 8));
          #pragma unroll
          for (int mi = 0; mi < 4; mi++)
            Oacc[mi][di] = __builtin_amdgcn_mfma_f32_16x16x32_bf16(pF[mi], vF, Oacc[mi][di], 0, 0, 0);
        }
      }
    }
  }
  float* dst = attnR + ((size_t)(n * RR + r)) * RS * 64;
  #pragma unroll
  for (int mi = 0; mi < 4; mi++) {
    #pragma unroll
    for (int jj = 0; jj < 4; jj++) {
      float inv = 1.f / lrun[mi * 4 + jj];
      int row = m0 + mi * 16 + hi * 4 + jj;
      #pragma unroll
      for (int di = 0; di < 4; di++)
        dst[row * 64 + di * 16 + lo] = Oacc[mi][di][jj] * inv;
    }
  }
}

// ---------------- lepe 5x5 dw + from_regions, per-region block, transposed layout ----------------
__global__ __launch_bounds__(256) void k_lepe2(const bf16* __restrict__ v_t, const float* __restrict__ attnR,
    const float* __restrict__ lw, const float* __restrict__ lb, bf16* __restrict__ z_t) {
  __shared__ bf16 sH[400 * 72];
  __shared__ float sW[25][64];
  int r = blockIdx.x, n = blockIdx.y;
  int rh = (r / 7) * 16, rw = (r % 7) * 16;
  int tid = threadIdx.x;
  for (int i = tid; i < 1600; i += 256) { int c = i / 25, k = i % 25; sW[k][c] = lw[c * 25 + k]; }
  for (int g = tid; g < 3200; g += 256) {
    int pix = g >> 3, c4 = g & 7;
    int yy = pix / 20, xx = pix % 20;
    int hh = rh + yy - 2, ww = rw + xx - 2;
    uint4 d = {0, 0, 0, 0};
    if ((unsigned)hh < HW && (unsigned)ww < HW)
      d = *(const uint4*)(v_t + ((size_t)n * PP + hh * HW + ww) * 64 + c4 * 8);
    *(uint4*)((char*)sH + pix * 144 + c4 * 16) = d;
  }
  __syncthreads();
  int y = tid >> 4, x = tid & 15;
  float acc[64];
  const float* ar = attnR + (((size_t)(n * RR + r)) * RS + tid) * 64;
  #pragma unroll
  for (int c = 0; c < 64; c++) acc[c] = lb[c] + ar[c];
  for (int t25 = 0; t25 < 25; t25++) {
    int dh = t25 / 5, dw = t25 % 5;
    int pix = (y + dh) * 20 + (x + dw);
    #pragma unroll
    for (int c8 = 0; c8 < 8; c8++) {
      bf16x8 hv = *(const bf16x8*)((const char*)sH + pix * 144 + c8 * 16);
      #pragma unroll
      for (int j = 0; j < 8; j++) acc[c8 * 8 + j] += (float)hv[j] * sW[t25][c8 * 8 + j];
    }
  }
  bf16* zp = z_t + ((size_t)n * PP + (rh + y) * HW + rw + x) * 64;
  #pragma unroll
  for (int c8 = 0; c8 < 8; c8++) {
    bf16x8 o8;
    #pragma unroll
    for (int j = 0; j < 8; j++) o8[j] = (bf16)acc[c8 * 8 + j];
    *(bf16x8*)(zp + c8 * 8) = o8;
  }
}

// ---------------- final untranspose: x_t[p][c] -> out[c][p] ----------------
__global__ __launch_bounds__(256) void k_untr(const float* __restrict__ x_t, float* __restrict__ out) {
  __shared__ float tile[64][68];
  int n = blockIdx.y; int p0 = blockIdx.x * 64;
  int tid = threadIdx.x;
  #pragma unroll
  for (int it = 0; it < 4; it++) {
    int g = tid + it * 256;
    int row = g >> 4, q = g & 15;
    float4 d = *(const float4*)&x_t[((size_t)n * PP + p0 + row) * 64 + q * 4];
    *(float4*)&tile[row][q * 4] = d;
  }
  __syncthreads();
  #pragma unroll
  for (int it = 0; it < 4; it++) {
    int g = tid + it * 256;
    int c = g >> 4, q = g & 15;
    float4 v;
    v.x = tile[q * 4 + 0][c]; v.y = tile[q * 4 + 1][c];
    v.z = tile[q * 4 + 2][c]; v.w = tile[q * 4 + 3][c];
    *(float4*)&out[((size_t)(n * 64 + c)) * PP + p0 + q * 4] = v;
  }
}

extern "C" void kernel_launch(void* const* d_in, const int* in_sizes, int n_in,
                              void* d_out, int out_size, void* d_ws, size_t ws_size,
                              hipStream_t stream) {
  const float* ex0 = (const float*)d_in[0];
  const float* ex  = (const float*)d_in[1];
  const float* img = (const float*)d_in[2];
  const float* pre = (const float*)d_in[3];
  const float* c0w = (const float*)d_in[4];
  const float* c0b = (const float*)d_in[5];
  const float* ln1g = (const float*)d_in[6];
  const float* ln1b = (const float*)d_in[7];
  const float* ln2g = (const float*)d_in[8];
  const float* ln2b = (const float*)d_in[9];
  const float* qkvw = (const float*)d_in[10];
  const float* qkvb = (const float*)d_in[11];
  const float* lw = (const float*)d_in[12];
  const float* lb = (const float*)d_in[13];
  const float* pw = (const float*)d_in[14];
  const float* pb = (const float*)d_in[15];
  const float* f1w = (const float*)d_in[16];
  const float* f1b = (const float*)d_in[17];
  const float* f2w = (const float*)d_in[18];
  const float* f2b = (const float*)d_in[19];

  float* W = (float*)d_ws;
  size_t o = 0;
  float* xcat = W + o;         o += 6573056;
  float* x_t  = W + o;         o += 3211264;
  float* attnR = W + o;        o += 3211264;
  bf16* y_t  = (bf16*)(W + o); o += 1605632;
  bf16* h_t  = (bf16*)(W + o); o += 6422528;
  bf16* v_t  = (bf16*)(W + o); o += 1605632;
  bf16* z_t  = (bf16*)(W + o); o += 1605632;
  bf16* qR   = (bf16*)(W + o); o += 1605632;
  bf16* kR   = (bf16*)(W + o); o += 1605632;
  bf16* vT   = (bf16*)(W + o); o += 1605632;
  float* qd = W + o;           o += 12544;
  float* kd = W + o;           o += 12544;
  float* maskr = W + o;        o += 50176;
  float* wT = W + o;           o += 75456;
  int* gidx = (int*)(W + o);   o += 784;

  k_prep<<<dim3((BB * 131 * PP + 255) / 256), dim3(256), 0, stream>>>(ex0, ex, img, pre, xcat, maskr);
  k_wt<<<dim3((131 * 9 * 64 + 255) / 256), dim3(256), 0, stream>>>(c0w, wT);
  k_conv0<<<dim3(7, 28, BB), dim3(256), 0, stream>>>(xcat, wT, c0b, x_t);
  for (int i = 0; i < 4; i++) {
    k_lnT<<<dim3((BB * PP + 255) / 256), dim3(256), 0, stream>>>(x_t, ln1g + i * 64, ln1b + i * 64, y_t);
    k_mgemm<0><<<dim3(98, 3, BB), dim3(256), 0, stream>>>(y_t, qkvw + (size_t)i * 192 * 64, qkvb + i * 192,
        64, nullptr, nullptr, qR, kR, vT, v_t);
    k_qdkd2<<<dim3(BB * RR), dim3(256), 0, stream>>>(qR, kR, qd, kd);
    k_topk<<<dim3(BB), dim3(64), 0, stream>>>(qd, kd, gidx);
    k_attn<<<dim3(BB * RR), dim3(256), 0, stream>>>(qR, kR, vT, maskr, gidx, attnR);
    k_lepe2<<<dim3(RR, BB), dim3(256), 0, stream>>>(v_t, attnR, lw + (size_t)i * 64 * 25, lb + i * 64, z_t);
    k_mgemm<2><<<dim3(98, 1, BB), dim3(256), 0, stream>>>(z_t, pw + (size_t)i * 64 * 64, pb + i * 64,
        64, x_t, nullptr, nullptr, nullptr, nullptr, nullptr);
    k_lnT<<<dim3((BB * PP + 255) / 256), dim3(256), 0, stream>>>(x_t, ln2g + i * 64, ln2b + i * 64, y_t);
    k_mgemm<1><<<dim3(98, 4, BB), dim3(256), 0, stream>>>(y_t, f1w + (size_t)i * 256 * 64, f1b + i * 256,
        64, nullptr, h_t, nullptr, nullptr, nullptr, nullptr);
    k_mgemm<2><<<dim3(98, 1, BB), dim3(256), 0, stream>>>(h_t, f2w + (size_t)i * 64 * 256, f2b + i * 64,
        256, x_t, nullptr, nullptr, nullptr, nullptr, nullptr);
  }
  k_untr<<<dim3(196, BB), dim3(256), 0, stream>>>(x_t, (float*)d_out);
}

// Round 3
// 991.175 us; speedup vs baseline: 1.7336x; 1.1065x over previous
//
#include <hip/hip_runtime.h>

#define HW 112
#define PP 12544
#define BB 4
#define RR 49
#define RS 256
#define GW 114          // padded grid width (zero ring)
#define GP (GW*GW)      // 12996
#define CK 160          // padded channels for conv0

typedef __bf16 bf16;
typedef __bf16 bf16x8 __attribute__((ext_vector_type(8)));
typedef __bf16 bf16x4 __attribute__((ext_vector_type(4)));
typedef float f32x4 __attribute__((ext_vector_type(4)));

// XOR-swizzled byte offset in a row-major bf16 tile; rowbytes ∈ {128,256,512}
__device__ __forceinline__ int swzg(int row, int halfcol, int rowbytes) {
  int byte = halfcol * 2;
  return row * rowbytes + (byte & ~127) + ((((byte >> 4) ^ row) & 7) * 16) + (byte & 15);
}
__device__ __forceinline__ int swz128(int row, int halfcol) { return swzg(row, halfcol, 128); }

__device__ __forceinline__ float gelu_exact(float x) {
  return 0.5f * x * (1.f + erff(x * 0.70710678118654752f));
}

// ---------------- prep: downsample+concat -> xcat_t bf16 [n][grid 114x114][160], mask ----------------
__global__ __launch_bounds__(256) void k_prep2(const float* __restrict__ ex0, const float* __restrict__ ex,
    const float* __restrict__ img, const float* __restrict__ pre,
    bf16* __restrict__ xct, float* __restrict__ maskr) {
  __shared__ bf16 sT2[64 * 168];   // [pixel][168 ch] rows 336B (16B aligned)
  int n = blockIdx.y;
  int p0 = blockIdx.x * 64;
  int tid = threadIdx.x;
  uint4 zz = {0, 0, 0, 0};
  for (int i2 = tid; i2 < 1344; i2 += 256) ((uint4*)sT2)[i2] = zz;
  __syncthreads();
  int l = tid & 63, g = tid >> 6;
  int p = p0 + l;
  int h = p / HW, w = p % HW;
  for (int c = g; c < 131; c += 4) {
    float val;
    if (c < 64) {
      const float* s = ex0 + (((size_t)(n * 64 + c)) * 224 + 2 * h) * 224 + 2 * w;
      val = 0.5f * (0.5f * (s[0] + s[224]) + 0.5f * (s[1] + s[225]));
    } else if (c < 128) {
      val = ex[((size_t)(n * 64 + (c - 64))) * PP + p];
    } else {
      const float* s = img + (((size_t)(n * 3 + (c - 128))) * 224 + 2 * h) * 224 + 2 * w;
      val = 0.5f * (0.5f * (s[0] + s[224]) + 0.5f * (s[1] + s[225]));
    }
    sT2[l * 168 + c] = (bf16)val;
  }
  if (tid < 64) {
    const float* s = pre + ((size_t)n * 224 + 2 * h) * 224 + 2 * w;
    float v = 0.5f * (0.5f * (s[0] + s[224]) + 0.5f * (s[1] + s[225]));
    int r = (h >> 4) * 7 + (w >> 4); int sIdx = (h & 15) * 16 + (w & 15);
    maskr[(n * RR + r) * RS + sIdx] = (v > 0.0f) ? 0.0f : -100.0f;
  }
  __syncthreads();
  for (int i2 = tid; i2 < 1280; i2 += 256) {
    int row = i2 / 20, ch = i2 % 20;
    int pr = p0 + row;
    int hh = pr / HW, ww = pr % HW;
    uint4 d = *(const uint4*)(sT2 + row * 168 + ch * 8);
    *(uint4*)(xct + ((size_t)n * GP + (hh + 1) * GW + ww + 1) * CK + ch * 8) = d;
  }
}

// ---------------- conv0 weights -> wTb bf16 [9tap][5ks][64o][32c] ----------------
__global__ __launch_bounds__(256) void k_wt2(const float* __restrict__ w, bf16* __restrict__ wTb) {
  int t = blockIdx.x * 256 + threadIdx.x;
  if (t >= 9 * 5 * 64 * 32) return;
  int cc = t & 31; int o = (t >> 5) & 63; int ks = (t >> 11) % 5; int k = t / 10240;
  int c = ks * 32 + cc;
  wTb[t] = (bf16)((c < 131) ? w[((size_t)(o * 131) + c) * 9 + k] : 0.f);
}

// ---------------- conv0 as MFMA implicit GEMM: 9 shifted taps x 5 K-slices ----------------
__global__ __launch_bounds__(256) void k_conv0m(const bf16* __restrict__ xct, const bf16* __restrict__ wTb,
    const float* __restrict__ bias, float* __restrict__ out_t) {
  __shared__ bf16 sA[128 * 32];   // [128 rows][32c] rows 64B
  __shared__ bf16 sB[64 * 32];    // [64 o][32c]
  int n = blockIdx.y;
  int p0 = blockIdx.x * 128;
  int tid = threadIdx.x, lane = tid & 63, wv = tid >> 6;
  int lo = lane & 15, hi = lane >> 4;
  // per-thread A staging: 512 uint4, idx = tid + it*256
  size_t gofsA[2];
  #pragma unroll
  for (int it = 0; it < 2; it++) {
    int idx = tid + it * 256;
    int row = idx >> 2, ch = idx & 3;
    int p = p0 + row;
    int hh = p / HW, ww = p % HW;
    gofsA[it] = ((size_t)(hh + 1) * GW + ww + 1) * (CK * 2) + ch * 16;
  }
  const char* xbase = (const char*)(xct + (size_t)n * GP * CK);
  f32x4 acc[2][4];
  #pragma unroll
  for (int mi = 0; mi < 2; mi++)
    #pragma unroll
    for (int ni = 0; ni < 4; ni++) acc[mi][ni] = (f32x4){0.f, 0.f, 0.f, 0.f};
  for (int tap = 0; tap < 9; tap++) {
    long shift = (long)((tap / 3 - 1) * GW + (tap % 3 - 1)) * (CK * 2);
    for (int ks = 0; ks < 5; ks++) {
      uint4 a0 = *(const uint4*)(xbase + gofsA[0] + shift + ks * 64);
      uint4 a1 = *(const uint4*)(xbase + gofsA[1] + shift + ks * 64);
      uint4 b0 = *(const uint4*)((const char*)wTb + ((size_t)(tap * 5 + ks) * 2048 + tid * 8) * 2);
      __syncthreads();
      *(uint4*)((char*)sA + tid * 16) = a0;
      *(uint4*)((char*)sA + (tid + 256) * 16) = a1;
      *(uint4*)((char*)sB + tid * 16) = b0;
      __syncthreads();
      bf16x8 aF[2], bF[4];
      #pragma unroll
      for (int mi = 0; mi < 2; mi++)
        aF[mi] = *(const bf16x8*)((const char*)sA + (wv * 32 + mi * 16 + lo) * 64 + hi * 16);
      #pragma unroll
      for (int ni = 0; ni < 4; ni++)
        bF[ni] = *(const bf16x8*)((const char*)sB + (ni * 16 + lo) * 64 + hi * 16);
      #pragma unroll
      for (int mi = 0; mi < 2; mi++)
        #pragma unroll
        for (int ni = 0; ni < 4; ni++)
          acc[mi][ni] = __builtin_amdgcn_mfma_f32_16x16x32_bf16(aF[mi], bF[ni], acc[mi][ni], 0, 0, 0);
    }
  }
  #pragma unroll
  for (int ni = 0; ni < 4; ni++) {
    float bv = bias[ni * 16 + lo];
    #pragma unroll
    for (int mi = 0; mi < 2; mi++) {
      #pragma unroll
      for (int r2 = 0; r2 < 4; r2++) {
        int p = p0 + wv * 32 + mi * 16 + hi * 4 + r2;
        out_t[((size_t)n * PP + p) * 64 + ni * 16 + lo] = acc[mi][ni][r2] + bv;
      }
    }
  }
}

// ---------------- LayerNorm: x_t[p][64] f32 -> y_t[p][64] bf16 ----------------
__global__ __launch_bounds__(256) void k_lnT(const float* __restrict__ x, const float* __restrict__ g,
    const float* __restrict__ b, bf16* __restrict__ y) {
  int t = blockIdx.x * 256 + threadIdx.x;
  if (t >= BB * PP) return;
  const float* xp = x + (size_t)t * 64;
  float v[64]; float mu = 0.f;
  #pragma unroll
  for (int i = 0; i < 16; i++) {
    float4 d = *(const float4*)&xp[i * 4];
    v[i * 4] = d.x; v[i * 4 + 1] = d.y; v[i * 4 + 2] = d.z; v[i * 4 + 3] = d.w;
    mu += d.x + d.y + d.z + d.w;
  }
  mu *= (1.f / 64.f);
  float var = 0.f;
  #pragma unroll
  for (int c = 0; c < 64; c++) { float d = v[c] - mu; var += d * d; }
  var *= (1.f / 64.f);
  float rs = rsqrtf(var + 1e-5f);
  bf16* yp = y + (size_t)t * 64;
  #pragma unroll
  for (int i = 0; i < 8; i++) {
    bf16x8 o8;
    #pragma unroll
    for (int j = 0; j < 8; j++) {
      int c = i * 8 + j;
      o8[j] = (bf16)((v[c] - mu) * rs * g[c] + b[c]);
    }
    *(bf16x8*)(yp + i * 8) = o8;
  }
}

// ---------------- qkv: one block does all 3 o-blocks (A staged once) ----------------
__global__ __launch_bounds__(256) void k_qkv(const bf16* __restrict__ A, const float* __restrict__ w,
    const float* __restrict__ bias, bf16* __restrict__ qRo, bf16* __restrict__ kRo, bf16* __restrict__ vto) {
  __shared__ bf16 sA[128 * 64];
  __shared__ bf16 sB[64 * 64];
  int n = blockIdx.y;
  int p0 = blockIdx.x * 128;
  int tid = threadIdx.x, lane = tid & 63, wv = tid >> 6;
  int lo = lane & 15, hi = lane >> 4;
  const bf16* Abase = A + (size_t)n * PP * 64;
  #pragma unroll
  for (int it = 0; it < 4; it++) {
    int idx = tid + it * 256;
    int row = idx >> 3, c4 = idx & 7;
    uint4 d = *(const uint4*)(Abase + (size_t)(p0 + row) * 64 + c4 * 8);
    *(uint4*)((char*)sA + row * 128 + (((c4 ^ row) & 7) * 16)) = d;
  }
  for (int ob = 0; ob < 3; ob++) {
    #pragma unroll
    for (int it = 0; it < 4; it++) {
      int idx = tid + it * 256;
      int oo = idx >> 4, q = idx & 15;
      float4 wv4 = *(const float4*)&w[(size_t)(ob * 64 + oo) * 64 + q * 4];
      bf16x4 b4; b4[0] = (bf16)wv4.x; b4[1] = (bf16)wv4.y; b4[2] = (bf16)wv4.z; b4[3] = (bf16)wv4.w;
      *(bf16x4*)((char*)sB + swz128(oo, q * 4)) = b4;
    }
    __syncthreads();
    f32x4 acc[2][4];
    #pragma unroll
    for (int mi = 0; mi < 2; mi++)
      #pragma unroll
      for (int ni = 0; ni < 4; ni++) acc[mi][ni] = (f32x4){0.f, 0.f, 0.f, 0.f};
    #pragma unroll
    for (int kk = 0; kk < 2; kk++) {
      bf16x8 aF[2], bF[4];
      #pragma unroll
      for (int mi = 0; mi < 2; mi++)
        aF[mi] = *(const bf16x8*)((const char*)sA + swz128(wv * 32 + mi * 16 + lo, kk * 32 + hi * 8));
      #pragma unroll
      for (int ni = 0; ni < 4; ni++)
        bF[ni] = *(const bf16x8*)((const char*)sB + swz128(ni * 16 + lo, kk * 32 + hi * 8));
      #pragma unroll
      for (int mi = 0; mi < 2; mi++)
        #pragma unroll
        for (int ni = 0; ni < 4; ni++)
          acc[mi][ni] = __builtin_amdgcn_mfma_f32_16x16x32_bf16(aF[mi], bF[ni], acc[mi][ni], 0, 0, 0);
    }
    #pragma unroll
    for (int ni = 0; ni < 4; ni++) {
      float bv = bias[ob * 64 + ni * 16 + lo];
      #pragma unroll
      for (int mi = 0; mi < 2; mi++) {
        #pragma unroll
        for (int r2 = 0; r2 < 4; r2++) {
          float rv = acc[mi][ni][r2] + bv;
          int p = p0 + wv * 32 + mi * 16 + hi * 4 + r2;
          int hh = p / HW, ww = p % HW;
          int rg = (hh >> 4) * 7 + (ww >> 4), s = (hh & 15) * 16 + (ww & 15);
          int o = ni * 16 + lo;
          if (ob == 0)      qRo[(((size_t)(n * RR + rg)) * RS + s) * 64 + o] = (bf16)(rv * 0.125f);
          else if (ob == 1) kRo[(((size_t)(n * RR + rg)) * RS + s) * 64 + o] = (bf16)rv;
          else              vto[((size_t)n * PP + p) * 64 + o] = (bf16)rv;
        }
      }
    }
    __syncthreads();
  }
}

// ---------------- per-region: vT transpose + qd/kd means ----------------
__global__ __launch_bounds__(256) void k_vpost(const bf16* __restrict__ qR, const bf16* __restrict__ kR,
    const bf16* __restrict__ v_t, float* __restrict__ qd, float* __restrict__ kd, bf16* __restrict__ vT) {
  __shared__ bf16 sT[64 * 264];
  __shared__ float rq[4][64], rk[4][64];
  int r = blockIdx.x, n = blockIdx.y;
  int nr = n * RR + r;
  int tid = threadIdx.x;
  int rh = (r / 7) * 16, rw = (r % 7) * 16;
  {  // transpose V region: read pixel rows, write columns
    int ph = rh + (tid >> 4), pw = rw + (tid & 15);
    const bf16* src = v_t + ((size_t)n * PP + ph * HW + pw) * 64;
    #pragma unroll
    for (int c8 = 0; c8 < 8; c8++) {
      bf16x8 d = *(const bf16x8*)(src + c8 * 8);
      #pragma unroll
      for (int j = 0; j < 8; j++) sT[(c8 * 8 + j) * 264 + tid] = d[j];
    }
  }
  {  // qd/kd partial sums
    int c = tid & 63, sq = tid >> 6;
    const bf16* qb = qR + (size_t)nr * RS * 64;
    const bf16* kb = kR + (size_t)nr * RS * 64;
    float aq = 0.f, ak = 0.f;
    for (int s = sq * 64; s < sq * 64 + 64; s++) {
      aq += (float)qb[s * 64 + c];
      ak += (float)kb[s * 64 + c];
    }
    rq[sq][c] = aq; rk[sq][c] = ak;
  }
  __syncthreads();
  #pragma unroll
  for (int it = 0; it < 8; it++) {
    int idx = tid + it * 256;
    int row = idx >> 5, ch = idx & 31;
    uint4 d = *(const uint4*)(sT + row * 264 + ch * 8);
    *(uint4*)(vT + ((size_t)nr * 64 + row) * 256 + ch * 8) = d;
  }
  if (tid < 64) {
    int c = tid;
    qd[(n * 64 + c) * RR + r] = ((rq[0][c] + rq[1][c]) + (rq[2][c] + rq[3][c])) * (1.f / 256.f);
    kd[(n * 64 + c) * RR + r] = ((rk[0][c] + rk[1][c]) + (rk[2][c] + rk[3][c])) * (1.f / 256.f);
  }
}

// ---------------- top-4 routing: one wave per query region ----------------
__global__ __launch_bounds__(64) void k_topk(const float* __restrict__ qd, const float* __restrict__ kd,
    int* __restrict__ gidx) {
  int pq = blockIdx.x, n = blockIdx.y;
  int j = threadIdx.x;
  float a = -3e38f;
  if (j < RR) {
    a = 0.f;
    for (int c = 0; c < 64; c++)
      a += qd[(n * 64 + c) * RR + pq] * kd[(n * 64 + c) * RR + j];
  }
  for (int t = 0; t < 4; t++) {
    float bv = a; int bj = j;
    #pragma unroll
    for (int d = 32; d >= 1; d >>= 1) {
      float ov = __shfl_xor(bv, d, 64);
      int oj = __shfl_xor(bj, d, 64);
      if (ov > bv || (ov == bv && oj < bj)) { bv = ov; bj = oj; }
    }
    if (j == 0) gidx[(n * RR + pq) * 4 + t] = bj;
    if (j == bj) a = -3e38f;
  }
}

// ---------------- gathered-region flash attention: no barriers, frags from L2 ----------------
__global__ __launch_bounds__(256) void k_attn(const bf16* __restrict__ qR, const bf16* __restrict__ kR,
    const bf16* __restrict__ vT, const float* __restrict__ maskr, const int* __restrict__ gidx,
    float* __restrict__ attnR) {
  __shared__ bf16 sP[4][64 * 64];
  int nb = blockIdx.x; int n = nb / RR, r = nb % RR;
  int tid = threadIdx.x, lane = tid & 63, wv = tid >> 6;
  int lo = lane & 15, hi = lane >> 4;
  int m0 = wv * 64;
  const bf16* qbase = qR + ((size_t)(n * RR + r)) * RS * 64;
  bf16x8 qF[4][2];
  #pragma unroll
  for (int mi = 0; mi < 4; mi++)
    #pragma unroll
    for (int kk = 0; kk < 2; kk++)
      qF[mi][kk] = *(const bf16x8*)(qbase + (m0 + mi * 16 + lo) * 64 + kk * 32 + hi * 8);

  f32x4 zero4 = {0.f, 0.f, 0.f, 0.f};
  f32x4 Oacc[4][4];
  #pragma unroll
  for (int mi = 0; mi < 4; mi++)
    #pragma unroll
    for (int di = 0; di < 4; di++) Oacc[mi][di] = zero4;
  float mrun[16], lrun[16];
  #pragma unroll
  for (int s = 0; s < 16; s++) { mrun[s] = -3e38f; lrun[s] = 0.f; }

  for (int t = 0; t < 4; t++) {
    int j = gidx[(n * RR + r) * 4 + t];
    const bf16* kbase = kR + ((size_t)(n * RR + j)) * RS * 64;
    const bf16* vbase = vT + ((size_t)(n * RR + j)) * 64 * RS;
    const float* mbase = maskr + (n * RR + j) * RS;
    for (int sub = 0; sub < 4; sub++) {
      f32x4 Sacc[4][4];
      #pragma unroll
      for (int mi = 0; mi < 4; mi++)
        #pragma unroll
        for (int ni = 0; ni < 4; ni++) Sacc[mi][ni] = zero4;
      #pragma unroll
      for (int kk = 0; kk < 2; kk++) {
        #pragma unroll
        for (int ni = 0; ni < 4; ni++) {
          bf16x8 bF = *(const bf16x8*)(kbase + (sub * 64 + ni * 16 + lo) * 64 + kk * 32 + hi * 8);
          #pragma unroll
          for (int mi = 0; mi < 4; mi++)
            Sacc[mi][ni] = __builtin_amdgcn_mfma_f32_16x16x32_bf16(qF[mi][kk], bF, Sacc[mi][ni], 0, 0, 0);
        }
      }
      float mv[4];
      #pragma unroll
      for (int ni = 0; ni < 4; ni++) mv[ni] = mbase[sub * 64 + ni * 16 + lo];
      bf16* sPw = sP[wv];
      #pragma unroll
      for (int mi = 0; mi < 4; mi++) {
        #pragma unroll
        for (int jj = 0; jj < 4; jj++) {
          int slot = mi * 4 + jj;
          float cm = fmaxf(fmaxf(Sacc[mi][0][jj] + mv[0], Sacc[mi][1][jj] + mv[1]),
                           fmaxf(Sacc[mi][2][jj] + mv[2], Sacc[mi][3][jj] + mv[3]));
          #pragma unroll
          for (int d2 = 1; d2 < 16; d2 <<= 1) cm = fmaxf(cm, __shfl_xor(cm, d2, 64));
          float nm = fmaxf(mrun[slot], cm);
          float sc = __expf(mrun[slot] - nm);
          float rsum = 0.f; float pv[4];
          #pragma unroll
          for (int ni = 0; ni < 4; ni++) { pv[ni] = __expf(Sacc[mi][ni][jj] + mv[ni] - nm); rsum += pv[ni]; }
          #pragma unroll
          for (int d2 = 1; d2 < 16; d2 <<= 1) rsum += __shfl_xor(rsum, d2, 64);
          mrun[slot] = nm; lrun[slot] = lrun[slot] * sc + rsum;
          #pragma unroll
          for (int di = 0; di < 4; di++) Oacc[mi][di][jj] *= sc;
          int prow = mi * 16 + hi * 4 + jj;
          #pragma unroll
          for (int ni = 0; ni < 4; ni++)
            *(bf16*)((char*)sPw + swz128(prow, ni * 16 + lo)) = (bf16)pv[ni];
        }
      }
      #pragma unroll
      for (int kk = 0; kk < 2; kk++) {
        bf16x8 pF[4];
        #pragma unroll
        for (int mi = 0; mi < 4; mi++)
          pF[mi] = *(const bf16x8*)((const char*)sPw + swz128(mi * 16 + lo, kk * 32 + hi * 8));
        #pragma unroll
        for (int di = 0; di < 4; di++) {
          bf16x8 vF = *(const bf16x8*)(vbase + (di * 16 + lo) * 256 + sub * 64 + kk * 32 + hi * 8);
          #pragma unroll
          for (int mi = 0; mi < 4; mi++)
            Oacc[mi][di] = __builtin_amdgcn_mfma_f32_16x16x32_bf16(pF[mi], vF, Oacc[mi][di], 0, 0, 0);
        }
      }
    }
  }
  float* dst = attnR + ((size_t)(n * RR + r)) * RS * 64;
  #pragma unroll
  for (int mi = 0; mi < 4; mi++) {
    #pragma unroll
    for (int jj = 0; jj < 4; jj++) {
      float inv = 1.f / lrun[mi * 4 + jj];
      int row = m0 + mi * 16 + hi * 4 + jj;
      #pragma unroll
      for (int di = 0; di < 4; di++)
        dst[row * 64 + di * 16 + lo] = Oacc[mi][di][jj] * inv;
    }
  }
}

// ---------------- lepe 5x5 dw + from_regions ----------------
__global__ __launch_bounds__(256) void k_lepe2(const bf16* __restrict__ v_t, const float* __restrict__ attnR,
    const float* __restrict__ lw, const float* __restrict__ lb, bf16* __restrict__ z_t) {
  __shared__ bf16 sH[400 * 72];
  __shared__ float sW[25][64];
  int r = blockIdx.x, n = blockIdx.y;
  int rh = (r / 7) * 16, rw = (r % 7) * 16;
  int tid = threadIdx.x;
  for (int i = tid; i < 1600; i += 256) { int c = i / 25, k = i % 25; sW[k][c] = lw[c * 25 + k]; }
  for (int g = tid; g < 3200; g += 256) {
    int pix = g >> 3, c4 = g & 7;
    int yy = pix / 20, xx = pix % 20;
    int hh = rh + yy - 2, ww = rw + xx - 2;
    uint4 d = {0, 0, 0, 0};
    if ((unsigned)hh < HW && (unsigned)ww < HW)
      d = *(const uint4*)(v_t + ((size_t)n * PP + hh * HW + ww) * 64 + c4 * 8);
    *(uint4*)((char*)sH + pix * 144 + c4 * 16) = d;
  }
  __syncthreads();
  int y = tid >> 4, x = tid & 15;
  float acc[64];
  const float* ar = attnR + (((size_t)(n * RR + r)) * RS + tid) * 64;
  #pragma unroll
  for (int c = 0; c < 64; c++) acc[c] = lb[c] + ar[c];
  for (int t25 = 0; t25 < 25; t25++) {
    int dh = t25 / 5, dw = t25 % 5;
    int pix = (y + dh) * 20 + (x + dw);
    #pragma unroll
    for (int c8 = 0; c8 < 8; c8++) {
      bf16x8 hv = *(const bf16x8*)((const char*)sH + pix * 144 + c8 * 16);
      #pragma unroll
      for (int j = 0; j < 8; j++) acc[c8 * 8 + j] += (float)hv[j] * sW[t25][c8 * 8 + j];
    }
  }
  bf16* zp = z_t + ((size_t)n * PP + (rh + y) * HW + rw + x) * 64;
  #pragma unroll
  for (int c8 = 0; c8 < 8; c8++) {
    bf16x8 o8;
    #pragma unroll
    for (int j = 0; j < 8; j++) o8[j] = (bf16)acc[c8 * 8 + j];
    *(bf16x8*)(zp + c8 * 8) = o8;
  }
}

// ---------------- proj GEMM: z_t -> x_t += ----------------
__global__ __launch_bounds__(256) void k_proj(const bf16* __restrict__ A, const float* __restrict__ w,
    const float* __restrict__ bias, float* __restrict__ xo) {
  __shared__ bf16 sA[128 * 64];
  __shared__ bf16 sB[64 * 64];
  int n = blockIdx.y;
  int p0 = blockIdx.x * 128;
  int tid = threadIdx.x, lane = tid & 63, wv = tid >> 6;
  int lo = lane & 15, hi = lane >> 4;
  const bf16* Abase = A + (size_t)n * PP * 64;
  #pragma unroll
  for (int it = 0; it < 4; it++) {
    int idx = tid + it * 256;
    int row = idx >> 3, c4 = idx & 7;
    uint4 d = *(const uint4*)(Abase + (size_t)(p0 + row) * 64 + c4 * 8);
    *(uint4*)((char*)sA + row * 128 + (((c4 ^ row) & 7) * 16)) = d;
  }
  #pragma unroll
  for (int it = 0; it < 4; it++) {
    int idx = tid + it * 256;
    int oo = idx >> 4, q = idx & 15;
    float4 wv4 = *(const float4*)&w[(size_t)oo * 64 + q * 4];
    bf16x4 b4; b4[0] = (bf16)wv4.x; b4[1] = (bf16)wv4.y; b4[2] = (bf16)wv4.z; b4[3] = (bf16)wv4.w;
    *(bf16x4*)((char*)sB + swz128(oo, q * 4)) = b4;
  }
  __syncthreads();
  f32x4 acc[2][4];
  #pragma unroll
  for (int mi = 0; mi < 2; mi++)
    #pragma unroll
    for (int ni = 0; ni < 4; ni++) acc[mi][ni] = (f32x4){0.f, 0.f, 0.f, 0.f};
  #pragma unroll
  for (int kk = 0; kk < 2; kk++) {
    bf16x8 aF[2], bF[4];
    #pragma unroll
    for (int mi = 0; mi < 2; mi++)
      aF[mi] = *(const bf16x8*)((const char*)sA + swz128(wv * 32 + mi * 16 + lo, kk * 32 + hi * 8));
    #pragma unroll
    for (int ni = 0; ni < 4; ni++)
      bF[ni] = *(const bf16x8*)((const char*)sB + swz128(ni * 16 + lo, kk * 32 + hi * 8));
    #pragma unroll
    for (int mi = 0; mi < 2; mi++)
      #pragma unroll
      for (int ni = 0; ni < 4; ni++)
        acc[mi][ni] = __builtin_amdgcn_mfma_f32_16x16x32_bf16(aF[mi], bF[ni], acc[mi][ni], 0, 0, 0);
  }
  #pragma unroll
  for (int ni = 0; ni < 4; ni++) {
    float bv = bias[ni * 16 + lo];
    #pragma unroll
    for (int mi = 0; mi < 2; mi++) {
      #pragma unroll
      for (int r2 = 0; r2 < 4; r2++) {
        int p = p0 + wv * 32 + mi * 16 + hi * 4 + r2;
        xo[((size_t)n * PP + p) * 64 + ni * 16 + lo] += acc[mi][ni][r2] + bv;
      }
    }
  }
}

// ---------------- fused MLP: fc1 + gelu + fc2 + residual (h stays in LDS) ----------------
__global__ __launch_bounds__(256) void k_mlp(const bf16* __restrict__ A, const float* __restrict__ w1,
    const float* __restrict__ b1, const float* __restrict__ w2, const float* __restrict__ b2,
    float* __restrict__ xo) {
  __shared__ bf16 sA[64 * 64];      // [64][64] swz128, 8KB
  __shared__ bf16 sW1[128 * 64];    // [128][64] swz128, 16KB (half of fc1 outs)
  __shared__ bf16 sHh[64 * 128];    // [64][128] swz256, 16KB
  __shared__ bf16 sW2[64 * 128];    // [64][128] swz256, 16KB (half of fc2 K)
  int n = blockIdx.y;
  int p0 = blockIdx.x * 64;
  int tid = threadIdx.x, lane = tid & 63, wv = tid >> 6;
  int lo = lane & 15, hi = lane >> 4;
  const bf16* Abase = A + (size_t)n * PP * 64;
  #pragma unroll
  for (int it = 0; it < 2; it++) {
    int idx = tid + it * 256;
    int row = idx >> 3, c4 = idx & 7;
    uint4 d = *(const uint4*)(Abase + (size_t)(p0 + row) * 64 + c4 * 8);
    *(uint4*)((char*)sA + row * 128 + (((c4 ^ row) & 7) * 16)) = d;
  }
  f32x4 oacc[4];
  #pragma unroll
  for (int ni = 0; ni < 4; ni++) oacc[ni] = (f32x4){0.f, 0.f, 0.f, 0.f};
  for (int half = 0; half < 2; half++) {
    #pragma unroll
    for (int it = 0; it < 8; it++) {
      int idx = tid + it * 256;
      int oo = idx >> 4, q = idx & 15;
      float4 wv4 = *(const float4*)&w1[(size_t)(half * 128 + oo) * 64 + q * 4];
      bf16x4 b4; b4[0] = (bf16)wv4.x; b4[1] = (bf16)wv4.y; b4[2] = (bf16)wv4.z; b4[3] = (bf16)wv4.w;
      *(bf16x4*)((char*)sW1 + swz128(oo, q * 4)) = b4;
    }
    __syncthreads();
    f32x4 hacc[8];
    #pragma unroll
    for (int ni = 0; ni < 8; ni++) hacc[ni] = (f32x4){0.f, 0.f, 0.f, 0.f};
    #pragma unroll
    for (int kk = 0; kk < 2; kk++) {
      bf16x8 aF = *(const bf16x8*)((const char*)sA + swz128(wv * 16 + lo, kk * 32 + hi * 8));
      #pragma unroll
      for (int ni = 0; ni < 8; ni++) {
        bf16x8 bF = *(const bf16x8*)((const char*)sW1 + swz128(ni * 16 + lo, kk * 32 + hi * 8));
        hacc[ni] = __builtin_amdgcn_mfma_f32_16x16x32_bf16(aF, bF, hacc[ni], 0, 0, 0);
      }
    }
    // gelu -> sHh (each wave writes only its own 16 rows)
    #pragma unroll
    for (int ni = 0; ni < 8; ni++) {
      float bv = b1[half * 128 + ni * 16 + lo];
      #pragma unroll
      for (int r2 = 0; r2 < 4; r2++) {
        float hval = gelu_exact(hacc[ni][r2] + bv);
        *(bf16*)((char*)sHh + swzg(wv * 16 + hi * 4 + r2, ni * 16 + lo, 256)) = (bf16)hval;
      }
    }
    #pragma unroll
    for (int it = 0; it < 8; it++) {
      int idx = tid + it * 256;
      int oo = idx >> 5, q = idx & 31;
      float4 wv4 = *(const float4*)&w2[(size_t)oo * 256 + half * 128 + q * 4];
      bf16x4 b4; b4[0] = (bf16)wv4.x; b4[1] = (bf16)wv4.y; b4[2] = (bf16)wv4.z; b4[3] = (bf16)wv4.w;
      *(bf16x4*)((char*)sW2 + swzg(oo, q * 4, 256)) = b4;
    }
    __syncthreads();
    #pragma unroll
    for (int kk = 0; kk < 4; kk++) {
      bf16x8 aH = *(const bf16x8*)((const char*)sHh + swzg(wv * 16 + lo, kk * 32 + hi * 8, 256));
      #pragma unroll
      for (int ni = 0; ni < 4; ni++) {
        bf16x8 bF = *(const bf16x8*)((const char*)sW2 + swzg(ni * 16 + lo, kk * 32 + hi * 8, 256));
        oacc[ni] = __builtin_amdgcn_mfma_f32_16x16x32_bf16(aH, bF, oacc[ni], 0, 0, 0);
      }
    }
    __syncthreads();
  }
  #pragma unroll
  for (int ni = 0; ni < 4; ni++) {
    float bv = b2[ni * 16 + lo];
    #pragma unroll
    for (int r2 = 0; r2 < 4; r2++) {
      int p = p0 + wv * 16 + hi * 4 + r2;
      xo[((size_t)n * PP + p) * 64 + ni * 16 + lo] += oacc[ni][r2] + bv;
    }
  }
}

// ---------------- final untranspose: x_t[p][c] -> out[c][p] ----------------
__global__ __launch_bounds__(256) void k_untr(const float* __restrict__ x_t, float* __restrict__ out) {
  __shared__ float tile[64][68];
  int n = blockIdx.y; int p0 = blockIdx.x * 64;
  int tid = threadIdx.x;
  #pragma unroll
  for (int it = 0; it < 4; it++) {
    int g = tid + it * 256;
    int row = g >> 4, q = g & 15;
    float4 d = *(const float4*)&x_t[((size_t)n * PP + p0 + row) * 64 + q * 4];
    *(float4*)&tile[row][q * 4] = d;
  }
  __syncthreads();
  #pragma unroll
  for (int it = 0; it < 4; it++) {
    int g = tid + it * 256;
    int c = g >> 4, q = g & 15;
    float4 v;
    v.x = tile[q * 4 + 0][c]; v.y = tile[q * 4 + 1][c];
    v.z = tile[q * 4 + 2][c]; v.w = tile[q * 4 + 3][c];
    *(float4*)&out[((size_t)(n * 64 + c)) * PP + p0 + q * 4] = v;
  }
}

extern "C" void kernel_launch(void* const* d_in, const int* in_sizes, int n_in,
                              void* d_out, int out_size, void* d_ws, size_t ws_size,
                              hipStream_t stream) {
  const float* ex0 = (const float*)d_in[0];
  const float* ex  = (const float*)d_in[1];
  const float* img = (const float*)d_in[2];
  const float* pre = (const float*)d_in[3];
  const float* c0w = (const float*)d_in[4];
  const float* c0b = (const float*)d_in[5];
  const float* ln1g = (const float*)d_in[6];
  const float* ln1b = (const float*)d_in[7];
  const float* ln2g = (const float*)d_in[8];
  const float* ln2b = (const float*)d_in[9];
  const float* qkvw = (const float*)d_in[10];
  const float* qkvb = (const float*)d_in[11];
  const float* lw = (const float*)d_in[12];
  const float* lb = (const float*)d_in[13];
  const float* pw = (const float*)d_in[14];
  const float* pb = (const float*)d_in[15];
  const float* f1w = (const float*)d_in[16];
  const float* f1b = (const float*)d_in[17];
  const float* f2w = (const float*)d_in[18];
  const float* f2b = (const float*)d_in[19];

  float* W = (float*)d_ws;
  size_t o = 0;
  bf16* xct = (bf16*)(W + o);  o += (size_t)BB * GP * CK / 2;   // 4,158,720
  float* x_t  = W + o;         o += 3211264;
  float* attnR = W + o;        o += 3211264;
  bf16* y_t  = (bf16*)(W + o); o += 1605632;
  bf16* v_t  = (bf16*)(W + o); o += 1605632;
  bf16* z_t  = (bf16*)(W + o); o += 1605632;
  bf16* qR   = (bf16*)(W + o); o += 1605632;
  bf16* kR   = (bf16*)(W + o); o += 1605632;
  bf16* vT   = (bf16*)(W + o); o += 1605632;
  float* qd = W + o;           o += 12544;
  float* kd = W + o;           o += 12544;
  float* maskr = W + o;        o += 50176;
  bf16* wTb = (bf16*)(W + o);  o += 46080;
  int* gidx = (int*)(W + o);   o += 784;

  hipMemsetAsync(xct, 0, (size_t)BB * GP * CK * 2, stream);
  k_prep2<<<dim3(196, BB), dim3(256), 0, stream>>>(ex0, ex, img, pre, xct, maskr);
  k_wt2<<<dim3(360), dim3(256), 0, stream>>>(c0w, wTb);
  k_conv0m<<<dim3(98, BB), dim3(256), 0, stream>>>(xct, wTb, c0b, x_t);
  for (int i = 0; i < 4; i++) {
    k_lnT<<<dim3(196), dim3(256), 0, stream>>>(x_t, ln1g + i * 64, ln1b + i * 64, y_t);
    k_qkv<<<dim3(98, BB), dim3(256), 0, stream>>>(y_t, qkvw + (size_t)i * 192 * 64, qkvb + i * 192,
        qR, kR, v_t);
    k_vpost<<<dim3(RR, BB), dim3(256), 0, stream>>>(qR, kR, v_t, qd, kd, vT);
    k_topk<<<dim3(RR, BB), dim3(64), 0, stream>>>(qd, kd, gidx);
    k_attn<<<dim3(BB * RR), dim3(256), 0, stream>>>(qR, kR, vT, maskr, gidx, attnR);
    k_lepe2<<<dim3(RR, BB), dim3(256), 0, stream>>>(v_t, attnR, lw + (size_t)i * 64 * 25, lb + i * 64, z_t);
    k_proj<<<dim3(98, BB), dim3(256), 0, stream>>>(z_t, pw + (size_t)i * 64 * 64, pb + i * 64, x_t);
    k_lnT<<<dim3(196), dim3(256), 0, stream>>>(x_t, ln2g + i * 64, ln2b + i * 64, y_t);
    k_mlp<<<dim3(196, BB), dim3(256), 0, stream>>>(y_t, f1w + (size_t)i * 256 * 64, f1b + i * 256,
        f2w + (size_t)i * 64 * 256, f2b + i * 64, x_t);
  }
  k_untr<<<dim3(196, BB), dim3(256), 0, stream>>>(x_t, (float*)d_out);
}

// Round 4
// 941.227 us; speedup vs baseline: 1.8256x; 1.0531x over previous
//
#include <hip/hip_runtime.h>

#define HW 112
#define PP 12544
#define BB 4
#define RR 49
#define RS 256
#define GW 114          // padded grid width (zero ring)
#define GP (GW*GW)      // 12996
#define CK 160          // padded channels for conv0

typedef __bf16 bf16;
typedef __bf16 bf16x8 __attribute__((ext_vector_type(8)));
typedef __bf16 bf16x4 __attribute__((ext_vector_type(4)));
typedef float f32x4 __attribute__((ext_vector_type(4)));

// XOR-swizzled byte offset in a row-major bf16 tile; rowbytes ∈ {128,256,512}
__device__ __forceinline__ int swzg(int row, int halfcol, int rowbytes) {
  int byte = halfcol * 2;
  return row * rowbytes + (byte & ~127) + ((((byte >> 4) ^ row) & 7) * 16) + (byte & 15);
}
__device__ __forceinline__ int swz128(int row, int halfcol) { return swzg(row, halfcol, 128); }

__device__ __forceinline__ float gelu_exact(float x) {
  return 0.5f * x * (1.f + erff(x * 0.70710678118654752f));
}

// ---------------- prep: downsample+concat -> xcat_t bf16 [n][grid 114x114][160], mask ----------------
__global__ __launch_bounds__(256) void k_prep2(const float* __restrict__ ex0, const float* __restrict__ ex,
    const float* __restrict__ img, const float* __restrict__ pre,
    bf16* __restrict__ xct, float* __restrict__ maskr) {
  __shared__ bf16 sT2[64 * 168];   // [pixel][168 ch] rows 336B (16B aligned)
  int n = blockIdx.y;
  int p0 = blockIdx.x * 64;
  int tid = threadIdx.x;
  uint4 zz = {0, 0, 0, 0};
  for (int i2 = tid; i2 < 1344; i2 += 256) ((uint4*)sT2)[i2] = zz;
  __syncthreads();
  int l = tid & 63, g = tid >> 6;
  int p = p0 + l;
  int h = p / HW, w = p % HW;
  for (int c = g; c < 131; c += 4) {
    float val;
    if (c < 64) {
      const float* s = ex0 + (((size_t)(n * 64 + c)) * 224 + 2 * h) * 224 + 2 * w;
      val = 0.5f * (0.5f * (s[0] + s[224]) + 0.5f * (s[1] + s[225]));
    } else if (c < 128) {
      val = ex[((size_t)(n * 64 + (c - 64))) * PP + p];
    } else {
      const float* s = img + (((size_t)(n * 3 + (c - 128))) * 224 + 2 * h) * 224 + 2 * w;
      val = 0.5f * (0.5f * (s[0] + s[224]) + 0.5f * (s[1] + s[225]));
    }
    sT2[l * 168 + c] = (bf16)val;
  }
  if (tid < 64) {
    const float* s = pre + ((size_t)n * 224 + 2 * h) * 224 + 2 * w;
    float v = 0.5f * (0.5f * (s[0] + s[224]) + 0.5f * (s[1] + s[225]));
    int r = (h >> 4) * 7 + (w >> 4); int sIdx = (h & 15) * 16 + (w & 15);
    maskr[(n * RR + r) * RS + sIdx] = (v > 0.0f) ? 0.0f : -100.0f;
  }
  __syncthreads();
  for (int i2 = tid; i2 < 1280; i2 += 256) {
    int row = i2 / 20, ch = i2 % 20;
    int pr = p0 + row;
    int hh = pr / HW, ww = pr % HW;
    uint4 d = *(const uint4*)(sT2 + row * 168 + ch * 8);
    *(uint4*)(xct + ((size_t)n * GP + (hh + 1) * GW + ww + 1) * CK + ch * 8) = d;
  }
}

// ---------------- conv0 weights -> wTb bf16 [9tap][5ks][64o][32c] ----------------
__global__ __launch_bounds__(256) void k_wt2(const float* __restrict__ w, bf16* __restrict__ wTb) {
  int t = blockIdx.x * 256 + threadIdx.x;
  if (t >= 9 * 5 * 64 * 32) return;
  int cc = t & 31; int o = (t >> 5) & 63; int ks = (t >> 11) % 5; int k = t / 10240;
  int c = ks * 32 + cc;
  wTb[t] = (bf16)((c < 131) ? w[((size_t)(o * 131) + c) * 9 + k] : 0.f);
}

// ---------------- conv0 as MFMA implicit GEMM: 9 shifted taps x 5 K-slices ----------------
__global__ __launch_bounds__(256) void k_conv0m(const bf16* __restrict__ xct, const bf16* __restrict__ wTb,
    const float* __restrict__ bias, float* __restrict__ out_t) {
  __shared__ bf16 sA[128 * 32];
  __shared__ bf16 sB[64 * 32];
  int n = blockIdx.y;
  int p0 = blockIdx.x * 128;
  int tid = threadIdx.x, lane = tid & 63, wv = tid >> 6;
  int lo = lane & 15, hi = lane >> 4;
  size_t gofsA[2];
  #pragma unroll
  for (int it = 0; it < 2; it++) {
    int idx = tid + it * 256;
    int row = idx >> 2, ch = idx & 3;
    int p = p0 + row;
    int hh = p / HW, ww = p % HW;
    gofsA[it] = ((size_t)(hh + 1) * GW + ww + 1) * (CK * 2) + ch * 16;
  }
  const char* xbase = (const char*)(xct + (size_t)n * GP * CK);
  f32x4 acc[2][4];
  #pragma unroll
  for (int mi = 0; mi < 2; mi++)
    #pragma unroll
    for (int ni = 0; ni < 4; ni++) acc[mi][ni] = (f32x4){0.f, 0.f, 0.f, 0.f};
  for (int tap = 0; tap < 9; tap++) {
    long shift = (long)((tap / 3 - 1) * GW + (tap % 3 - 1)) * (CK * 2);
    for (int ks = 0; ks < 5; ks++) {
      uint4 a0 = *(const uint4*)(xbase + gofsA[0] + shift + ks * 64);
      uint4 a1 = *(const uint4*)(xbase + gofsA[1] + shift + ks * 64);
      uint4 b0 = *(const uint4*)((const char*)wTb + ((size_t)(tap * 5 + ks) * 2048 + tid * 8) * 2);
      __syncthreads();
      *(uint4*)((char*)sA + tid * 16) = a0;
      *(uint4*)((char*)sA + (tid + 256) * 16) = a1;
      *(uint4*)((char*)sB + tid * 16) = b0;
      __syncthreads();
      bf16x8 aF[2], bF[4];
      #pragma unroll
      for (int mi = 0; mi < 2; mi++)
        aF[mi] = *(const bf16x8*)((const char*)sA + (wv * 32 + mi * 16 + lo) * 64 + hi * 16);
      #pragma unroll
      for (int ni = 0; ni < 4; ni++)
        bF[ni] = *(const bf16x8*)((const char*)sB + (ni * 16 + lo) * 64 + hi * 16);
      #pragma unroll
      for (int mi = 0; mi < 2; mi++)
        #pragma unroll
        for (int ni = 0; ni < 4; ni++)
          acc[mi][ni] = __builtin_amdgcn_mfma_f32_16x16x32_bf16(aF[mi], bF[ni], acc[mi][ni], 0, 0, 0);
    }
  }
  #pragma unroll
  for (int ni = 0; ni < 4; ni++) {
    float bv = bias[ni * 16 + lo];
    #pragma unroll
    for (int mi = 0; mi < 2; mi++) {
      #pragma unroll
      for (int r2 = 0; r2 < 4; r2++) {
        int p = p0 + wv * 32 + mi * 16 + hi * 4 + r2;
        out_t[((size_t)n * PP + p) * 64 + ni * 16 + lo] = acc[mi][ni][r2] + bv;
      }
    }
  }
}

// ---------------- qkv with fused LN1 ----------------
__global__ __launch_bounds__(256) void k_qkv(const float* __restrict__ xin, const float* __restrict__ lng,
    const float* __restrict__ lnb, const float* __restrict__ w, const float* __restrict__ bias,
    bf16* __restrict__ qRo, bf16* __restrict__ kRo, bf16* __restrict__ vto) {
  __shared__ bf16 sA[128 * 64];
  __shared__ bf16 sB[64 * 64];
  int n = blockIdx.y;
  int p0 = blockIdx.x * 128;
  int tid = threadIdx.x, lane = tid & 63, wv = tid >> 6;
  int lo = lane & 15, hi = lane >> 4;
  { // fused LN staging: 2 threads per row, 32 channels each
    int row = tid >> 1, part = tid & 1;
    const float* xp = xin + ((size_t)n * PP + p0 + row) * 64 + part * 32;
    float v[32]; float s = 0.f, sq = 0.f;
    #pragma unroll
    for (int i = 0; i < 8; i++) {
      float4 d = *(const float4*)&xp[i * 4];
      v[i*4]=d.x; v[i*4+1]=d.y; v[i*4+2]=d.z; v[i*4+3]=d.w;
      s += d.x+d.y+d.z+d.w;
      sq += d.x*d.x+d.y*d.y+d.z*d.z+d.w*d.w;
    }
    s += __shfl_xor(s, 1, 64); sq += __shfl_xor(sq, 1, 64);
    float mu = s * (1.f/64.f);
    float rstd = rsqrtf(fmaxf(sq * (1.f/64.f) - mu*mu, 0.f) + 1e-5f);
    #pragma unroll
    for (int j2 = 0; j2 < 4; j2++) {
      bf16x8 o8;
      #pragma unroll
      for (int e = 0; e < 8; e++) {
        int c = part*32 + j2*8 + e;
        o8[e] = (bf16)((v[j2*8+e] - mu) * rstd * lng[c] + lnb[c]);
      }
      *(bf16x8*)((char*)sA + swz128(row, part*32 + j2*8)) = o8;
    }
  }
  for (int ob = 0; ob < 3; ob++) {
    #pragma unroll
    for (int it = 0; it < 4; it++) {
      int idx = tid + it * 256;
      int oo = idx >> 4, q = idx & 15;
      float4 wv4 = *(const float4*)&w[(size_t)(ob * 64 + oo) * 64 + q * 4];
      bf16x4 b4; b4[0] = (bf16)wv4.x; b4[1] = (bf16)wv4.y; b4[2] = (bf16)wv4.z; b4[3] = (bf16)wv4.w;
      *(bf16x4*)((char*)sB + swz128(oo, q * 4)) = b4;
    }
    __syncthreads();
    f32x4 acc[2][4];
    #pragma unroll
    for (int mi = 0; mi < 2; mi++)
      #pragma unroll
      for (int ni = 0; ni < 4; ni++) acc[mi][ni] = (f32x4){0.f, 0.f, 0.f, 0.f};
    #pragma unroll
    for (int kk = 0; kk < 2; kk++) {
      bf16x8 aF[2], bF[4];
      #pragma unroll
      for (int mi = 0; mi < 2; mi++)
        aF[mi] = *(const bf16x8*)((const char*)sA + swz128(wv * 32 + mi * 16 + lo, kk * 32 + hi * 8));
      #pragma unroll
      for (int ni = 0; ni < 4; ni++)
        bF[ni] = *(const bf16x8*)((const char*)sB + swz128(ni * 16 + lo, kk * 32 + hi * 8));
      #pragma unroll
      for (int mi = 0; mi < 2; mi++)
        #pragma unroll
        for (int ni = 0; ni < 4; ni++)
          acc[mi][ni] = __builtin_amdgcn_mfma_f32_16x16x32_bf16(aF[mi], bF[ni], acc[mi][ni], 0, 0, 0);
    }
    #pragma unroll
    for (int ni = 0; ni < 4; ni++) {
      float bv = bias[ob * 64 + ni * 16 + lo];
      #pragma unroll
      for (int mi = 0; mi < 2; mi++) {
        #pragma unroll
        for (int r2 = 0; r2 < 4; r2++) {
          float rv = acc[mi][ni][r2] + bv;
          int p = p0 + wv * 32 + mi * 16 + hi * 4 + r2;
          int hh = p / HW, ww = p % HW;
          int rg = (hh >> 4) * 7 + (ww >> 4), s2 = (hh & 15) * 16 + (ww & 15);
          int o = ni * 16 + lo;
          if (ob == 0)      qRo[(((size_t)(n * RR + rg)) * RS + s2) * 64 + o] = (bf16)(rv * 0.125f);
          else if (ob == 1) kRo[(((size_t)(n * RR + rg)) * RS + s2) * 64 + o] = (bf16)rv;
          else              vto[((size_t)n * PP + p) * 64 + o] = (bf16)rv;
        }
      }
    }
    __syncthreads();
  }
}

// ---------------- per-region: vT transpose + qd/kd means ----------------
__global__ __launch_bounds__(256) void k_vpost(const bf16* __restrict__ qR, const bf16* __restrict__ kR,
    const bf16* __restrict__ v_t, float* __restrict__ qd, float* __restrict__ kd, bf16* __restrict__ vT) {
  __shared__ bf16 sT[64 * 264];
  __shared__ float rq[4][64], rk[4][64];
  int r = blockIdx.x, n = blockIdx.y;
  int nr = n * RR + r;
  int tid = threadIdx.x;
  int rh = (r / 7) * 16, rw = (r % 7) * 16;
  {
    int ph = rh + (tid >> 4), pw = rw + (tid & 15);
    const bf16* src = v_t + ((size_t)n * PP + ph * HW + pw) * 64;
    #pragma unroll
    for (int c8 = 0; c8 < 8; c8++) {
      bf16x8 d = *(const bf16x8*)(src + c8 * 8);
      #pragma unroll
      for (int j = 0; j < 8; j++) sT[(c8 * 8 + j) * 264 + tid] = d[j];
    }
  }
  {
    int c = tid & 63, sq = tid >> 6;
    const bf16* qb = qR + (size_t)nr * RS * 64;
    const bf16* kb = kR + (size_t)nr * RS * 64;
    float aq = 0.f, ak = 0.f;
    for (int s = sq * 64; s < sq * 64 + 64; s++) {
      aq += (float)qb[s * 64 + c];
      ak += (float)kb[s * 64 + c];
    }
    rq[sq][c] = aq; rk[sq][c] = ak;
  }
  __syncthreads();
  #pragma unroll
  for (int it = 0; it < 8; it++) {
    int idx = tid + it * 256;
    int row = idx >> 5, ch = idx & 31;
    uint4 d = *(const uint4*)(sT + row * 264 + ch * 8);
    *(uint4*)(vT + ((size_t)nr * 64 + row) * 256 + ch * 8) = d;
  }
  if (tid < 64) {
    int c = tid;
    qd[(n * 64 + c) * RR + r] = ((rq[0][c] + rq[1][c]) + (rq[2][c] + rq[3][c])) * (1.f / 256.f);
    kd[(n * 64 + c) * RR + r] = ((rk[0][c] + rk[1][c]) + (rk[2][c] + rk[3][c])) * (1.f / 256.f);
  }
}

// ---------------- top-4 routing: one wave per query region ----------------
__global__ __launch_bounds__(64) void k_topk(const float* __restrict__ qd, const float* __restrict__ kd,
    int* __restrict__ gidx) {
  int pq = blockIdx.x, n = blockIdx.y;
  int j = threadIdx.x;
  float a = -3e38f;
  if (j < RR) {
    a = 0.f;
    for (int c = 0; c < 64; c++)
      a += qd[(n * 64 + c) * RR + pq] * kd[(n * 64 + c) * RR + j];
  }
  for (int t = 0; t < 4; t++) {
    float bv = a; int bj = j;
    #pragma unroll
    for (int d = 32; d >= 1; d >>= 1) {
      float ov = __shfl_xor(bv, d, 64);
      int oj = __shfl_xor(bj, d, 64);
      if (ov > bv || (ov == bv && oj < bj)) { bv = ov; bj = oj; }
    }
    if (j == 0) gidx[(n * RR + pq) * 4 + t] = bj;
    if (j == bj) a = -3e38f;
  }
}

// ---------------- gathered-region flash attention: 784 blocks, wave = 16 Q rows ----------------
__global__ __launch_bounds__(256) void k_attn(const bf16* __restrict__ qR, const bf16* __restrict__ kR,
    const bf16* __restrict__ vT, const float* __restrict__ maskr, const int* __restrict__ gidx,
    bf16* __restrict__ attnRb) {
  __shared__ bf16 sP[4][16 * 64];
  int nb = blockIdx.x;
  int n = nb / (RR * 4); int rem = nb % (RR * 4); int r = rem >> 2, qs = rem & 3;
  int tid = threadIdx.x, lane = tid & 63, wv = tid >> 6;
  int lo = lane & 15, hi = lane >> 4;
  int m0 = qs * 64 + wv * 16;
  const bf16* qbase = qR + ((size_t)(n * RR + r)) * RS * 64;
  bf16x8 qF[2];
  #pragma unroll
  for (int kk = 0; kk < 2; kk++)
    qF[kk] = *(const bf16x8*)(qbase + (m0 + lo) * 64 + kk * 32 + hi * 8);

  f32x4 zero4 = {0.f, 0.f, 0.f, 0.f};
  f32x4 Oacc[4];
  #pragma unroll
  for (int di = 0; di < 4; di++) Oacc[di] = zero4;
  float mrun[4], lrun[4];
  #pragma unroll
  for (int s = 0; s < 4; s++) { mrun[s] = -3e38f; lrun[s] = 0.f; }

  for (int t = 0; t < 4; t++) {
    int j = gidx[(n * RR + r) * 4 + t];
    const bf16* kbase = kR + ((size_t)(n * RR + j)) * RS * 64;
    const bf16* vbase = vT + ((size_t)(n * RR + j)) * 64 * RS;
    const float* mbase = maskr + (n * RR + j) * RS;
    for (int sub = 0; sub < 4; sub++) {
      f32x4 Sacc[4];
      #pragma unroll
      for (int ni = 0; ni < 4; ni++) Sacc[ni] = zero4;
      #pragma unroll
      for (int kk = 0; kk < 2; kk++) {
        #pragma unroll
        for (int ni = 0; ni < 4; ni++) {
          bf16x8 bF = *(const bf16x8*)(kbase + (sub * 64 + ni * 16 + lo) * 64 + kk * 32 + hi * 8);
          Sacc[ni] = __builtin_amdgcn_mfma_f32_16x16x32_bf16(qF[kk], bF, Sacc[ni], 0, 0, 0);
        }
      }
      float mv[4];
      #pragma unroll
      for (int ni = 0; ni < 4; ni++) mv[ni] = mbase[sub * 64 + ni * 16 + lo];
      bf16* sPw = sP[wv];
      #pragma unroll
      for (int jj = 0; jj < 4; jj++) {
        float cm = fmaxf(fmaxf(Sacc[0][jj] + mv[0], Sacc[1][jj] + mv[1]),
                         fmaxf(Sacc[2][jj] + mv[2], Sacc[3][jj] + mv[3]));
        #pragma unroll
        for (int d2 = 1; d2 < 16; d2 <<= 1) cm = fmaxf(cm, __shfl_xor(cm, d2, 64));
        float nm = fmaxf(mrun[jj], cm);
        float sc = __expf(mrun[jj] - nm);
        float rsum = 0.f; float pv[4];
        #pragma unroll
        for (int ni = 0; ni < 4; ni++) { pv[ni] = __expf(Sacc[ni][jj] + mv[ni] - nm); rsum += pv[ni]; }
        #pragma unroll
        for (int d2 = 1; d2 < 16; d2 <<= 1) rsum += __shfl_xor(rsum, d2, 64);
        mrun[jj] = nm; lrun[jj] = lrun[jj] * sc + rsum;
        #pragma unroll
        for (int di = 0; di < 4; di++) Oacc[di][jj] *= sc;
        int prow = hi * 4 + jj;
        #pragma unroll
        for (int ni = 0; ni < 4; ni++)
          *(bf16*)((char*)sPw + swz128(prow, ni * 16 + lo)) = (bf16)pv[ni];
      }
      #pragma unroll
      for (int kk = 0; kk < 2; kk++) {
        bf16x8 pF = *(const bf16x8*)((const char*)sPw + swz128(lo, kk * 32 + hi * 8));
        #pragma unroll
        for (int di = 0; di < 4; di++) {
          bf16x8 vF = *(const bf16x8*)(vbase + (di * 16 + lo) * 256 + sub * 64 + kk * 32 + hi * 8);
          Oacc[di] = __builtin_amdgcn_mfma_f32_16x16x32_bf16(pF, vF, Oacc[di], 0, 0, 0);
        }
      }
    }
  }
  bf16* dst = attnRb + ((size_t)(n * RR + r)) * RS * 64;
  #pragma unroll
  for (int jj = 0; jj < 4; jj++) {
    float inv = 1.f / lrun[jj];
    int row = m0 + hi * 4 + jj;
    #pragma unroll
    for (int di = 0; di < 4; di++)
      dst[row * 64 + di * 16 + lo] = (bf16)(Oacc[di][jj] * inv);
  }
}

// ---------------- lepe 5x5 dw + from_regions (attnR now bf16) ----------------
__global__ __launch_bounds__(256) void k_lepe2(const bf16* __restrict__ v_t, const bf16* __restrict__ attnRb,
    const float* __restrict__ lw, const float* __restrict__ lb, bf16* __restrict__ z_t) {
  __shared__ bf16 sH[400 * 72];
  __shared__ float sW[25][64];
  int r = blockIdx.x, n = blockIdx.y;
  int rh = (r / 7) * 16, rw = (r % 7) * 16;
  int tid = threadIdx.x;
  for (int i = tid; i < 1600; i += 256) { int c = i / 25, k = i % 25; sW[k][c] = lw[c * 25 + k]; }
  for (int g = tid; g < 3200; g += 256) {
    int pix = g >> 3, c4 = g & 7;
    int yy = pix / 20, xx = pix % 20;
    int hh = rh + yy - 2, ww = rw + xx - 2;
    uint4 d = {0, 0, 0, 0};
    if ((unsigned)hh < HW && (unsigned)ww < HW)
      d = *(const uint4*)(v_t + ((size_t)n * PP + hh * HW + ww) * 64 + c4 * 8);
    *(uint4*)((char*)sH + pix * 144 + c4 * 16) = d;
  }
  __syncthreads();
  int y = tid >> 4, x = tid & 15;
  float acc[64];
  const bf16* ar = attnRb + (((size_t)(n * RR + r)) * RS + tid) * 64;
  #pragma unroll
  for (int c8 = 0; c8 < 8; c8++) {
    bf16x8 av = *(const bf16x8*)(ar + c8 * 8);
    #pragma unroll
    for (int j = 0; j < 8; j++) acc[c8 * 8 + j] = lb[c8 * 8 + j] + (float)av[j];
  }
  for (int t25 = 0; t25 < 25; t25++) {
    int dh = t25 / 5, dw = t25 % 5;
    int pix = (y + dh) * 20 + (x + dw);
    #pragma unroll
    for (int c8 = 0; c8 < 8; c8++) {
      bf16x8 hv = *(const bf16x8*)((const char*)sH + pix * 144 + c8 * 16);
      #pragma unroll
      for (int j = 0; j < 8; j++) acc[c8 * 8 + j] += (float)hv[j] * sW[t25][c8 * 8 + j];
    }
  }
  bf16* zp = z_t + ((size_t)n * PP + (rh + y) * HW + rw + x) * 64;
  #pragma unroll
  for (int c8 = 0; c8 < 8; c8++) {
    bf16x8 o8;
    #pragma unroll
    for (int j = 0; j < 8; j++) o8[j] = (bf16)acc[c8 * 8 + j];
    *(bf16x8*)(zp + c8 * 8) = o8;
  }
}

// ---------------- proj GEMM: z_t -> x_t += ----------------
__global__ __launch_bounds__(256) void k_proj(const bf16* __restrict__ A, const float* __restrict__ w,
    const float* __restrict__ bias, float* __restrict__ xo) {
  __shared__ bf16 sA[128 * 64];
  __shared__ bf16 sB[64 * 64];
  int n = blockIdx.y;
  int p0 = blockIdx.x * 128;
  int tid = threadIdx.x, lane = tid & 63, wv = tid >> 6;
  int lo = lane & 15, hi = lane >> 4;
  const bf16* Abase = A + (size_t)n * PP * 64;
  #pragma unroll
  for (int it = 0; it < 4; it++) {
    int idx = tid + it * 256;
    int row = idx >> 3, c4 = idx & 7;
    uint4 d = *(const uint4*)(Abase + (size_t)(p0 + row) * 64 + c4 * 8);
    *(uint4*)((char*)sA + row * 128 + (((c4 ^ row) & 7) * 16)) = d;
  }
  #pragma unroll
  for (int it = 0; it < 4; it++) {
    int idx = tid + it * 256;
    int oo = idx >> 4, q = idx & 15;
    float4 wv4 = *(const float4*)&w[(size_t)oo * 64 + q * 4];
    bf16x4 b4; b4[0] = (bf16)wv4.x; b4[1] = (bf16)wv4.y; b4[2] = (bf16)wv4.z; b4[3] = (bf16)wv4.w;
    *(bf16x4*)((char*)sB + swz128(oo, q * 4)) = b4;
  }
  __syncthreads();
  f32x4 acc[2][4];
  #pragma unroll
  for (int mi = 0; mi < 2; mi++)
    #pragma unroll
    for (int ni = 0; ni < 4; ni++) acc[mi][ni] = (f32x4){0.f, 0.f, 0.f, 0.f};
  #pragma unroll
  for (int kk = 0; kk < 2; kk++) {
    bf16x8 aF[2], bF[4];
    #pragma unroll
    for (int mi = 0; mi < 2; mi++)
      aF[mi] = *(const bf16x8*)((const char*)sA + swz128(wv * 32 + mi * 16 + lo, kk * 32 + hi * 8));
    #pragma unroll
    for (int ni = 0; ni < 4; ni++)
      bF[ni] = *(const bf16x8*)((const char*)sB + swz128(ni * 16 + lo, kk * 32 + hi * 8));
    #pragma unroll
    for (int mi = 0; mi < 2; mi++)
      #pragma unroll
      for (int ni = 0; ni < 4; ni++)
        acc[mi][ni] = __builtin_amdgcn_mfma_f32_16x16x32_bf16(aF[mi], bF[ni], acc[mi][ni], 0, 0, 0);
  }
  #pragma unroll
  for (int ni = 0; ni < 4; ni++) {
    float bv = bias[ni * 16 + lo];
    #pragma unroll
    for (int mi = 0; mi < 2; mi++) {
      #pragma unroll
      for (int r2 = 0; r2 < 4; r2++) {
        int p = p0 + wv * 32 + mi * 16 + hi * 4 + r2;
        xo[((size_t)n * PP + p) * 64 + ni * 16 + lo] += acc[mi][ni][r2] + bv;
      }
    }
  }
}

// ---------------- fused MLP: LN2 + fc1 + gelu + fc2 + residual ----------------
__global__ __launch_bounds__(256) void k_mlp(const float* __restrict__ xin, const float* __restrict__ lng,
    const float* __restrict__ lnb, const float* __restrict__ w1, const float* __restrict__ b1,
    const float* __restrict__ w2, const float* __restrict__ b2, float* __restrict__ xo) {
  __shared__ bf16 sA[64 * 64];
  __shared__ bf16 sW1[128 * 64];
  __shared__ bf16 sHh[64 * 128];
  __shared__ bf16 sW2[64 * 128];
  int n = blockIdx.y;
  int p0 = blockIdx.x * 64;
  int tid = threadIdx.x, lane = tid & 63, wv = tid >> 6;
  int lo = lane & 15, hi = lane >> 4;
  { // fused LN staging: 4 threads per row, 16 channels each
    int row = tid >> 2, part = tid & 3;
    const float* xp = xin + ((size_t)n * PP + p0 + row) * 64 + part * 16;
    float v[16]; float s = 0.f, sq = 0.f;
    #pragma unroll
    for (int i = 0; i < 4; i++) {
      float4 d = *(const float4*)&xp[i * 4];
      v[i*4]=d.x; v[i*4+1]=d.y; v[i*4+2]=d.z; v[i*4+3]=d.w;
      s += d.x+d.y+d.z+d.w;
      sq += d.x*d.x+d.y*d.y+d.z*d.z+d.w*d.w;
    }
    s += __shfl_xor(s, 1, 64); sq += __shfl_xor(sq, 1, 64);
    s += __shfl_xor(s, 2, 64); sq += __shfl_xor(sq, 2, 64);
    float mu = s * (1.f/64.f);
    float rstd = rsqrtf(fmaxf(sq * (1.f/64.f) - mu*mu, 0.f) + 1e-5f);
    #pragma unroll
    for (int j2 = 0; j2 < 2; j2++) {
      bf16x8 o8;
      #pragma unroll
      for (int e = 0; e < 8; e++) {
        int c = part*16 + j2*8 + e;
        o8[e] = (bf16)((v[j2*8+e] - mu) * rstd * lng[c] + lnb[c]);
      }
      *(bf16x8*)((char*)sA + swz128(row, part*16 + j2*8)) = o8;
    }
  }
  f32x4 oacc[4];
  #pragma unroll
  for (int ni = 0; ni < 4; ni++) oacc[ni] = (f32x4){0.f, 0.f, 0.f, 0.f};
  for (int half = 0; half < 2; half++) {
    #pragma unroll
    for (int it = 0; it < 8; it++) {
      int idx = tid + it * 256;
      int oo = idx >> 4, q = idx & 15;
      float4 wv4 = *(const float4*)&w1[(size_t)(half * 128 + oo) * 64 + q * 4];
      bf16x4 b4; b4[0] = (bf16)wv4.x; b4[1] = (bf16)wv4.y; b4[2] = (bf16)wv4.z; b4[3] = (bf16)wv4.w;
      *(bf16x4*)((char*)sW1 + swz128(oo, q * 4)) = b4;
    }
    __syncthreads();
    f32x4 hacc[8];
    #pragma unroll
    for (int ni = 0; ni < 8; ni++) hacc[ni] = (f32x4){0.f, 0.f, 0.f, 0.f};
    #pragma unroll
    for (int kk = 0; kk < 2; kk++) {
      bf16x8 aF = *(const bf16x8*)((const char*)sA + swz128(wv * 16 + lo, kk * 32 + hi * 8));
      #pragma unroll
      for (int ni = 0; ni < 8; ni++) {
        bf16x8 bF = *(const bf16x8*)((const char*)sW1 + swz128(ni * 16 + lo, kk * 32 + hi * 8));
        hacc[ni] = __builtin_amdgcn_mfma_f32_16x16x32_bf16(aF, bF, hacc[ni], 0, 0, 0);
      }
    }
    #pragma unroll
    for (int ni = 0; ni < 8; ni++) {
      float bv = b1[half * 128 + ni * 16 + lo];
      #pragma unroll
      for (int r2 = 0; r2 < 4; r2++) {
        float hval = gelu_exact(hacc[ni][r2] + bv);
        *(bf16*)((char*)sHh + swzg(wv * 16 + hi * 4 + r2, ni * 16 + lo, 256)) = (bf16)hval;
      }
    }
    #pragma unroll
    for (int it = 0; it < 8; it++) {
      int idx = tid + it * 256;
      int oo = idx >> 5, q = idx & 31;
      float4 wv4 = *(const float4*)&w2[(size_t)oo * 256 + half * 128 + q * 4];
      bf16x4 b4; b4[0] = (bf16)wv4.x; b4[1] = (bf16)wv4.y; b4[2] = (bf16)wv4.z; b4[3] = (bf16)wv4.w;
      *(bf16x4*)((char*)sW2 + swzg(oo, q * 4, 256)) = b4;
    }
    __syncthreads();
    #pragma unroll
    for (int kk = 0; kk < 4; kk++) {
      bf16x8 aH = *(const bf16x8*)((const char*)sHh + swzg(wv * 16 + lo, kk * 32 + hi * 8, 256));
      #pragma unroll
      for (int ni = 0; ni < 4; ni++) {
        bf16x8 bF = *(const bf16x8*)((const char*)sW2 + swzg(ni * 16 + lo, kk * 32 + hi * 8, 256));
        oacc[ni] = __builtin_amdgcn_mfma_f32_16x16x32_bf16(aH, bF, oacc[ni], 0, 0, 0);
      }
    }
    __syncthreads();
  }
  #pragma unroll
  for (int ni = 0; ni < 4; ni++) {
    float bv = b2[ni * 16 + lo];
    #pragma unroll
    for (int r2 = 0; r2 < 4; r2++) {
      int p = p0 + wv * 16 + hi * 4 + r2;
      xo[((size_t)n * PP + p) * 64 + ni * 16 + lo] += oacc[ni][r2] + bv;
    }
  }
}

// ---------------- final untranspose: x_t[p][c] -> out[c][p] ----------------
__global__ __launch_bounds__(256) void k_untr(const float* __restrict__ x_t, float* __restrict__ out) {
  __shared__ float tile[64][68];
  int n = blockIdx.y; int p0 = blockIdx.x * 64;
  int tid = threadIdx.x;
  #pragma unroll
  for (int it = 0; it < 4; it++) {
    int g = tid + it * 256;
    int row = g >> 4, q = g & 15;
    float4 d = *(const float4*)&x_t[((size_t)n * PP + p0 + row) * 64 + q * 4];
    *(float4*)&tile[row][q * 4] = d;
  }
  __syncthreads();
  #pragma unroll
  for (int it = 0; it < 4; it++) {
    int g = tid + it * 256;
    int c = g >> 4, q = g & 15;
    float4 v;
    v.x = tile[q * 4 + 0][c]; v.y = tile[q * 4 + 1][c];
    v.z = tile[q * 4 + 2][c]; v.w = tile[q * 4 + 3][c];
    *(float4*)&out[((size_t)(n * 64 + c)) * PP + p0 + q * 4] = v;
  }
}

extern "C" void kernel_launch(void* const* d_in, const int* in_sizes, int n_in,
                              void* d_out, int out_size, void* d_ws, size_t ws_size,
                              hipStream_t stream) {
  const float* ex0 = (const float*)d_in[0];
  const float* ex  = (const float*)d_in[1];
  const float* img = (const float*)d_in[2];
  const float* pre = (const float*)d_in[3];
  const float* c0w = (const float*)d_in[4];
  const float* c0b = (const float*)d_in[5];
  const float* ln1g = (const float*)d_in[6];
  const float* ln1b = (const float*)d_in[7];
  const float* ln2g = (const float*)d_in[8];
  const float* ln2b = (const float*)d_in[9];
  const float* qkvw = (const float*)d_in[10];
  const float* qkvb = (const float*)d_in[11];
  const float* lw = (const float*)d_in[12];
  const float* lb = (const float*)d_in[13];
  const float* pw = (const float*)d_in[14];
  const float* pb = (const float*)d_in[15];
  const float* f1w = (const float*)d_in[16];
  const float* f1b = (const float*)d_in[17];
  const float* f2w = (const float*)d_in[18];
  const float* f2b = (const float*)d_in[19];

  float* W = (float*)d_ws;
  size_t o = 0;
  bf16* xct = (bf16*)(W + o);  o += (size_t)BB * GP * CK / 2;
  float* x_t  = W + o;         o += 3211264;
  bf16* attnRb = (bf16*)(W + o); o += 1605632;
  bf16* v_t  = (bf16*)(W + o); o += 1605632;
  bf16* z_t  = (bf16*)(W + o); o += 1605632;
  bf16* qR   = (bf16*)(W + o); o += 1605632;
  bf16* kR   = (bf16*)(W + o); o += 1605632;
  bf16* vT   = (bf16*)(W + o); o += 1605632;
  float* qd = W + o;           o += 12544;
  float* kd = W + o;           o += 12544;
  float* maskr = W + o;        o += 50176;
  bf16* wTb = (bf16*)(W + o);  o += 46080;
  int* gidx = (int*)(W + o);   o += 784;

  hipMemsetAsync(xct, 0, (size_t)BB * GP * CK * 2, stream);
  k_prep2<<<dim3(196, BB), dim3(256), 0, stream>>>(ex0, ex, img, pre, xct, maskr);
  k_wt2<<<dim3(360), dim3(256), 0, stream>>>(c0w, wTb);
  k_conv0m<<<dim3(98, BB), dim3(256), 0, stream>>>(xct, wTb, c0b, x_t);
  for (int i = 0; i < 4; i++) {
    k_qkv<<<dim3(98, BB), dim3(256), 0, stream>>>(x_t, ln1g + i * 64, ln1b + i * 64,
        qkvw + (size_t)i * 192 * 64, qkvb + i * 192, qR, kR, v_t);
    k_vpost<<<dim3(RR, BB), dim3(256), 0, stream>>>(qR, kR, v_t, qd, kd, vT);
    k_topk<<<dim3(RR, BB), dim3(64), 0, stream>>>(qd, kd, gidx);
    k_attn<<<dim3(BB * RR * 4), dim3(256), 0, stream>>>(qR, kR, vT, maskr, gidx, attnRb);
    k_lepe2<<<dim3(RR, BB), dim3(256), 0, stream>>>(v_t, attnRb, lw + (size_t)i * 64 * 25, lb + i * 64, z_t);
    k_proj<<<dim3(98, BB), dim3(256), 0, stream>>>(z_t, pw + (size_t)i * 64 * 64, pb + i * 64, x_t);
    k_mlp<<<dim3(196, BB), dim3(256), 0, stream>>>(x_t, ln2g + i * 64, ln2b + i * 64,
        f1w + (size_t)i * 256 * 64, f1b + i * 256, f2w + (size_t)i * 64 * 256, f2b + i * 64, x_t);
  }
  k_untr<<<dim3(196, BB), dim3(256), 0, stream>>>(x_t, (float*)d_out);
}

// Round 5
// 791.079 us; speedup vs baseline: 2.1721x; 1.1898x over previous
//
#include <hip/hip_runtime.h>

#define HW 112
#define PP 12544
#define BB 4
#define RR 49
#define RS 256
#define GW 114          // padded grid width (zero ring)
#define GP (GW*GW)      // 12996
#define CK 160          // padded channels for conv0

typedef __bf16 bf16;
typedef __bf16 bf16x8 __attribute__((ext_vector_type(8)));
typedef __bf16 bf16x4 __attribute__((ext_vector_type(4)));
typedef float f32x4 __attribute__((ext_vector_type(4)));

// XOR-swizzled byte offset in a row-major bf16 tile; rowbytes ∈ {128,256,512}
__device__ __forceinline__ int swzg(int row, int halfcol, int rowbytes) {
  int byte = halfcol * 2;
  return row * rowbytes + (byte & ~127) + ((((byte >> 4) ^ row) & 7) * 16) + (byte & 15);
}
__device__ __forceinline__ int swz128(int row, int halfcol) { return swzg(row, halfcol, 128); }

__device__ __forceinline__ float gelu_exact(float x) {
  return 0.5f * x * (1.f + erff(x * 0.70710678118654752f));
}

// ---------------- prep: downsample+concat -> xcat_t bf16 [n][grid 114x114][160], mask ----------------
__global__ __launch_bounds__(256) void k_prep2(const float* __restrict__ ex0, const float* __restrict__ ex,
    const float* __restrict__ img, const float* __restrict__ pre,
    bf16* __restrict__ xct, float* __restrict__ maskr) {
  __shared__ bf16 sT2[64 * 168];   // [pixel][168 ch] rows 336B (16B aligned)
  int n = blockIdx.y;
  int p0 = blockIdx.x * 64;
  int tid = threadIdx.x;
  uint4 zz = {0, 0, 0, 0};
  for (int i2 = tid; i2 < 1344; i2 += 256) ((uint4*)sT2)[i2] = zz;
  __syncthreads();
  int l = tid & 63, g = tid >> 6;
  int p = p0 + l;
  int h = p / HW, w = p % HW;
  for (int c = g; c < 131; c += 4) {
    float val;
    if (c < 64) {
      const float* s = ex0 + (((size_t)(n * 64 + c)) * 224 + 2 * h) * 224 + 2 * w;
      val = 0.5f * (0.5f * (s[0] + s[224]) + 0.5f * (s[1] + s[225]));
    } else if (c < 128) {
      val = ex[((size_t)(n * 64 + (c - 64))) * PP + p];
    } else {
      const float* s = img + (((size_t)(n * 3 + (c - 128))) * 224 + 2 * h) * 224 + 2 * w;
      val = 0.5f * (0.5f * (s[0] + s[224]) + 0.5f * (s[1] + s[225]));
    }
    sT2[l * 168 + c] = (bf16)val;
  }
  if (tid < 64) {
    const float* s = pre + ((size_t)n * 224 + 2 * h) * 224 + 2 * w;
    float v = 0.5f * (0.5f * (s[0] + s[224]) + 0.5f * (s[1] + s[225]));
    int r = (h >> 4) * 7 + (w >> 4); int sIdx = (h & 15) * 16 + (w & 15);
    maskr[(n * RR + r) * RS + sIdx] = (v > 0.0f) ? 0.0f : -100.0f;
  }
  __syncthreads();
  for (int i2 = tid; i2 < 1280; i2 += 256) {
    int row = i2 / 20, ch = i2 % 20;
    int pr = p0 + row;
    int hh = pr / HW, ww = pr % HW;
    uint4 d = *(const uint4*)(sT2 + row * 168 + ch * 8);
    *(uint4*)(xct + ((size_t)n * GP + (hh + 1) * GW + ww + 1) * CK + ch * 8) = d;
  }
}

// ---------------- conv0 weights -> wTb bf16 [9tap][5ks][64o][32c] ----------------
__global__ __launch_bounds__(256) void k_wt2(const float* __restrict__ w, bf16* __restrict__ wTb) {
  int t = blockIdx.x * 256 + threadIdx.x;
  if (t >= 9 * 5 * 64 * 32) return;
  int cc = t & 31; int o = (t >> 5) & 63; int ks = (t >> 11) % 5; int k = t / 10240;
  int c = ks * 32 + cc;
  wTb[t] = (bf16)((c < 131) ? w[((size_t)(o * 131) + c) * 9 + k] : 0.f);
}

// ---------------- conv0 as MFMA implicit GEMM: 9 shifted taps x 5 K-slices ----------------
__global__ __launch_bounds__(256) void k_conv0m(const bf16* __restrict__ xct, const bf16* __restrict__ wTb,
    const float* __restrict__ bias, float* __restrict__ out_t) {
  __shared__ bf16 sA[128 * 32];
  __shared__ bf16 sB[64 * 32];
  int n = blockIdx.y;
  int p0 = blockIdx.x * 128;
  int tid = threadIdx.x, lane = tid & 63, wv = tid >> 6;
  int lo = lane & 15, hi = lane >> 4;
  size_t gofsA[2];
  #pragma unroll
  for (int it = 0; it < 2; it++) {
    int idx = tid + it * 256;
    int row = idx >> 2, ch = idx & 3;
    int p = p0 + row;
    int hh = p / HW, ww = p % HW;
    gofsA[it] = ((size_t)(hh + 1) * GW + ww + 1) * (CK * 2) + ch * 16;
  }
  const char* xbase = (const char*)(xct + (size_t)n * GP * CK);
  f32x4 acc[2][4];
  #pragma unroll
  for (int mi = 0; mi < 2; mi++)
    #pragma unroll
    for (int ni = 0; ni < 4; ni++) acc[mi][ni] = (f32x4){0.f, 0.f, 0.f, 0.f};
  for (int tap = 0; tap < 9; tap++) {
    long shift = (long)((tap / 3 - 1) * GW + (tap % 3 - 1)) * (CK * 2);
    for (int ks = 0; ks < 5; ks++) {
      uint4 a0 = *(const uint4*)(xbase + gofsA[0] + shift + ks * 64);
      uint4 a1 = *(const uint4*)(xbase + gofsA[1] + shift + ks * 64);
      uint4 b0 = *(const uint4*)((const char*)wTb + ((size_t)(tap * 5 + ks) * 2048 + tid * 8) * 2);
      __syncthreads();
      *(uint4*)((char*)sA + tid * 16) = a0;
      *(uint4*)((char*)sA + (tid + 256) * 16) = a1;
      *(uint4*)((char*)sB + tid * 16) = b0;
      __syncthreads();
      bf16x8 aF[2], bF[4];
      #pragma unroll
      for (int mi = 0; mi < 2; mi++)
        aF[mi] = *(const bf16x8*)((const char*)sA + (wv * 32 + mi * 16 + lo) * 64 + hi * 16);
      #pragma unroll
      for (int ni = 0; ni < 4; ni++)
        bF[ni] = *(const bf16x8*)((const char*)sB + (ni * 16 + lo) * 64 + hi * 16);
      #pragma unroll
      for (int mi = 0; mi < 2; mi++)
        #pragma unroll
        for (int ni = 0; ni < 4; ni++)
          acc[mi][ni] = __builtin_amdgcn_mfma_f32_16x16x32_bf16(aF[mi], bF[ni], acc[mi][ni], 0, 0, 0);
    }
  }
  #pragma unroll
  for (int ni = 0; ni < 4; ni++) {
    float bv = bias[ni * 16 + lo];
    #pragma unroll
    for (int mi = 0; mi < 2; mi++) {
      #pragma unroll
      for (int r2 = 0; r2 < 4; r2++) {
        int p = p0 + wv * 32 + mi * 16 + hi * 4 + r2;
        out_t[((size_t)n * PP + p) * 64 + ni * 16 + lo] = acc[mi][ni][r2] + bv;
      }
    }
  }
}

// ---------------- qkv with fused LN1 ----------------
__global__ __launch_bounds__(256) void k_qkv(const float* __restrict__ xin, const float* __restrict__ lng,
    const float* __restrict__ lnb, const float* __restrict__ w, const float* __restrict__ bias,
    bf16* __restrict__ qRo, bf16* __restrict__ kRo, bf16* __restrict__ vto) {
  __shared__ bf16 sA[128 * 64];
  __shared__ bf16 sB[64 * 64];
  int n = blockIdx.y;
  int p0 = blockIdx.x * 128;
  int tid = threadIdx.x, lane = tid & 63, wv = tid >> 6;
  int lo = lane & 15, hi = lane >> 4;
  { // fused LN staging: 2 threads per row, 32 channels each
    int row = tid >> 1, part = tid & 1;
    const float* xp = xin + ((size_t)n * PP + p0 + row) * 64 + part * 32;
    float v[32]; float s = 0.f, sq = 0.f;
    #pragma unroll
    for (int i = 0; i < 8; i++) {
      float4 d = *(const float4*)&xp[i * 4];
      v[i*4]=d.x; v[i*4+1]=d.y; v[i*4+2]=d.z; v[i*4+3]=d.w;
      s += d.x+d.y+d.z+d.w;
      sq += d.x*d.x+d.y*d.y+d.z*d.z+d.w*d.w;
    }
    s += __shfl_xor(s, 1, 64); sq += __shfl_xor(sq, 1, 64);
    float mu = s * (1.f/64.f);
    float rstd = rsqrtf(fmaxf(sq * (1.f/64.f) - mu*mu, 0.f) + 1e-5f);
    #pragma unroll
    for (int j2 = 0; j2 < 4; j2++) {
      bf16x8 o8;
      #pragma unroll
      for (int e = 0; e < 8; e++) {
        int c = part*32 + j2*8 + e;
        o8[e] = (bf16)((v[j2*8+e] - mu) * rstd * lng[c] + lnb[c]);
      }
      *(bf16x8*)((char*)sA + swz128(row, part*32 + j2*8)) = o8;
    }
  }
  for (int ob = 0; ob < 3; ob++) {
    #pragma unroll
    for (int it = 0; it < 4; it++) {
      int idx = tid + it * 256;
      int oo = idx >> 4, q = idx & 15;
      float4 wv4 = *(const float4*)&w[(size_t)(ob * 64 + oo) * 64 + q * 4];
      bf16x4 b4; b4[0] = (bf16)wv4.x; b4[1] = (bf16)wv4.y; b4[2] = (bf16)wv4.z; b4[3] = (bf16)wv4.w;
      *(bf16x4*)((char*)sB + swz128(oo, q * 4)) = b4;
    }
    __syncthreads();
    f32x4 acc[2][4];
    #pragma unroll
    for (int mi = 0; mi < 2; mi++)
      #pragma unroll
      for (int ni = 0; ni < 4; ni++) acc[mi][ni] = (f32x4){0.f, 0.f, 0.f, 0.f};
    #pragma unroll
    for (int kk = 0; kk < 2; kk++) {
      bf16x8 aF[2], bF[4];
      #pragma unroll
      for (int mi = 0; mi < 2; mi++)
        aF[mi] = *(const bf16x8*)((const char*)sA + swz128(wv * 32 + mi * 16 + lo, kk * 32 + hi * 8));
      #pragma unroll
      for (int ni = 0; ni < 4; ni++)
        bF[ni] = *(const bf16x8*)((const char*)sB + swz128(ni * 16 + lo, kk * 32 + hi * 8));
      #pragma unroll
      for (int mi = 0; mi < 2; mi++)
        #pragma unroll
        for (int ni = 0; ni < 4; ni++)
          acc[mi][ni] = __builtin_amdgcn_mfma_f32_16x16x32_bf16(aF[mi], bF[ni], acc[mi][ni], 0, 0, 0);
    }
    #pragma unroll
    for (int ni = 0; ni < 4; ni++) {
      float bv = bias[ob * 64 + ni * 16 + lo];
      #pragma unroll
      for (int mi = 0; mi < 2; mi++) {
        #pragma unroll
        for (int r2 = 0; r2 < 4; r2++) {
          float rv = acc[mi][ni][r2] + bv;
          int p = p0 + wv * 32 + mi * 16 + hi * 4 + r2;
          int hh = p / HW, ww = p % HW;
          int rg = (hh >> 4) * 7 + (ww >> 4), s2 = (hh & 15) * 16 + (ww & 15);
          int o = ni * 16 + lo;
          if (ob == 0)      qRo[(((size_t)(n * RR + rg)) * RS + s2) * 64 + o] = (bf16)(rv * 0.125f);
          else if (ob == 1) kRo[(((size_t)(n * RR + rg)) * RS + s2) * 64 + o] = (bf16)rv;
          else              vto[((size_t)n * PP + p) * 64 + o] = (bf16)rv;
        }
      }
    }
    __syncthreads();
  }
}

// ---------------- per-region: vT transpose + qd/kd means ----------------
__global__ __launch_bounds__(256) void k_vpost(const bf16* __restrict__ qR, const bf16* __restrict__ kR,
    const bf16* __restrict__ v_t, float* __restrict__ qd, float* __restrict__ kd, bf16* __restrict__ vT) {
  __shared__ bf16 sT[64 * 264];
  __shared__ float rq[4][64], rk[4][64];
  int r = blockIdx.x, n = blockIdx.y;
  int nr = n * RR + r;
  int tid = threadIdx.x;
  int rh = (r / 7) * 16, rw = (r % 7) * 16;
  {
    int ph = rh + (tid >> 4), pw = rw + (tid & 15);
    const bf16* src = v_t + ((size_t)n * PP + ph * HW + pw) * 64;
    #pragma unroll
    for (int c8 = 0; c8 < 8; c8++) {
      bf16x8 d = *(const bf16x8*)(src + c8 * 8);
      #pragma unroll
      for (int j = 0; j < 8; j++) sT[(c8 * 8 + j) * 264 + tid] = d[j];
    }
  }
  {
    int c = tid & 63, sq = tid >> 6;
    const bf16* qb = qR + (size_t)nr * RS * 64;
    const bf16* kb = kR + (size_t)nr * RS * 64;
    float aq = 0.f, ak = 0.f;
    for (int s = sq * 64; s < sq * 64 + 64; s++) {
      aq += (float)qb[s * 64 + c];
      ak += (float)kb[s * 64 + c];
    }
    rq[sq][c] = aq; rk[sq][c] = ak;
  }
  __syncthreads();
  #pragma unroll
  for (int it = 0; it < 8; it++) {
    int idx = tid + it * 256;
    int row = idx >> 5, ch = idx & 31;
    uint4 d = *(const uint4*)(sT + row * 264 + ch * 8);
    *(uint4*)(vT + ((size_t)nr * 64 + row) * 256 + ch * 8) = d;
  }
  if (tid < 64) {
    int c = tid;
    qd[(n * 64 + c) * RR + r] = ((rq[0][c] + rq[1][c]) + (rq[2][c] + rq[3][c])) * (1.f / 256.f);
    kd[(n * 64 + c) * RR + r] = ((rk[0][c] + rk[1][c]) + (rk[2][c] + rk[3][c])) * (1.f / 256.f);
  }
}

// ---------------- top-4 routing: one wave per query region ----------------
__global__ __launch_bounds__(64) void k_topk(const float* __restrict__ qd, const float* __restrict__ kd,
    int* __restrict__ gidx) {
  int pq = blockIdx.x, n = blockIdx.y;
  int j = threadIdx.x;
  float a = -3e38f;
  if (j < RR) {
    a = 0.f;
    for (int c = 0; c < 64; c++)
      a += qd[(n * 64 + c) * RR + pq] * kd[(n * 64 + c) * RR + j];
  }
  for (int t = 0; t < 4; t++) {
    float bv = a; int bj = j;
    #pragma unroll
    for (int d = 32; d >= 1; d >>= 1) {
      float ov = __shfl_xor(bv, d, 64);
      int oj = __shfl_xor(bj, d, 64);
      if (ov > bv || (ov == bv && oj < bj)) { bv = ov; bj = oj; }
    }
    if (j == 0) gidx[(n * RR + pq) * 4 + t] = bj;
    if (j == bj) a = -3e38f;
  }
}

// ---------------- gathered-region flash attention: LDS-staged sub-tiles, pipelined ----------------
// grid = BB*RR*4 (XCD-swizzled); block = 4 waves; wave owns 16 Q rows
__global__ __launch_bounds__(256) void k_attn(const bf16* __restrict__ qR, const bf16* __restrict__ kR,
    const bf16* __restrict__ vT, const float* __restrict__ maskr, const int* __restrict__ gidx,
    bf16* __restrict__ attnRb) {
  __shared__ bf16 sK[64 * 64];
  __shared__ bf16 sV[64 * 64];
  __shared__ bf16 sP[4][16 * 64];
  __shared__ float sMask[256];
  int bid = blockIdx.x;
  int newid = (bid & 7) * 98 + (bid >> 3);   // 784 = 8*98: bijective XCD chunking
  int n = newid / (RR * 4); int rem = newid % (RR * 4); int r = rem >> 2, qs = rem & 3;
  int tid = threadIdx.x, lane = tid & 63, wv = tid >> 6;
  int lo = lane & 15, hi = lane >> 4;
  int m0 = qs * 64 + wv * 16;
  const bf16* qbase = qR + ((size_t)(n * RR + r)) * RS * 64;
  bf16x8 qF[2];
  #pragma unroll
  for (int kk = 0; kk < 2; kk++)
    qF[kk] = *(const bf16x8*)(qbase + (m0 + lo) * 64 + kk * 32 + hi * 8);

  // LDS write offsets (swizzled) for the 2×uint4 staging per array
  int wofs[2];
  #pragma unroll
  for (int it = 0; it < 2; it++) {
    int idx = tid + it * 256;
    int row = idx >> 3, c4 = idx & 7;
    wofs[it] = row * 128 + (((c4 ^ row) & 7) * 16);
  }
  int srcK[2], srcV[2];   // element offsets within tile (sub-independent parts)
  #pragma unroll
  for (int it = 0; it < 2; it++) {
    int idx = tid + it * 256;
    int row = idx >> 3, c4 = idx & 7;
    srcK[it] = row * 64 + c4 * 8;      // + sub*64*64 row shift handled via sub*4096
    srcV[it] = row * 256 + c4 * 8;     // + sub*64 col shift
  }

  f32x4 zero4 = {0.f, 0.f, 0.f, 0.f};
  f32x4 Oacc[4];
  #pragma unroll
  for (int di = 0; di < 4; di++) Oacc[di] = zero4;
  float mrun[4], lrun[4];
  #pragma unroll
  for (int s = 0; s < 4; s++) { mrun[s] = -3e38f; lrun[s] = 0.f; }

  const int* gptr = gidx + (n * RR + r) * 4;
  int j0 = gptr[0];
  const bf16* kbase = kR + ((size_t)(n * RR + j0)) * RS * 64;
  const bf16* vbase = vT + ((size_t)(n * RR + j0)) * 64 * RS;
  const float* mbase = maskr + (n * RR + j0) * RS;
  uint4 regK[2], regV[2]; float regM;
  // preload ts=0 (t=0, sub=0)
  #pragma unroll
  for (int it = 0; it < 2; it++) {
    regK[it] = *(const uint4*)(kbase + srcK[it]);
    regV[it] = *(const uint4*)(vbase + srcV[it]);
  }
  regM = mbase[tid];

  for (int ts = 0; ts < 16; ts++) {
    int sub = ts & 3;
    __syncthreads();   // all waves done reading LDS from previous iteration
    #pragma unroll
    for (int it = 0; it < 2; it++) {
      *(uint4*)((char*)sK + wofs[it]) = regK[it];
      *(uint4*)((char*)sV + wofs[it]) = regV[it];
    }
    if (sub == 0) sMask[tid] = regM;
    __syncthreads();
    // prefetch next sub while computing this one
    if (ts < 15) {
      int nts = ts + 1, nsub = nts & 3;
      if (nsub == 0) {
        int j = gptr[nts >> 2];
        kbase = kR + ((size_t)(n * RR + j)) * RS * 64;
        vbase = vT + ((size_t)(n * RR + j)) * 64 * RS;
        mbase = maskr + (n * RR + j) * RS;
        regM = mbase[tid];
      }
      #pragma unroll
      for (int it = 0; it < 2; it++) {
        regK[it] = *(const uint4*)(kbase + nsub * 4096 + srcK[it]);
        regV[it] = *(const uint4*)(vbase + nsub * 64 + srcV[it]);
      }
    }
    // ---- compute sub ----
    f32x4 Sacc[4];
    #pragma unroll
    for (int ni = 0; ni < 4; ni++) Sacc[ni] = zero4;
    #pragma unroll
    for (int kk = 0; kk < 2; kk++) {
      #pragma unroll
      for (int ni = 0; ni < 4; ni++) {
        bf16x8 bF = *(const bf16x8*)((const char*)sK + swz128(ni * 16 + lo, kk * 32 + hi * 8));
        Sacc[ni] = __builtin_amdgcn_mfma_f32_16x16x32_bf16(qF[kk], bF, Sacc[ni], 0, 0, 0);
      }
    }
    float mv[4];
    #pragma unroll
    for (int ni = 0; ni < 4; ni++) mv[ni] = sMask[sub * 64 + ni * 16 + lo];
    bf16* sPw = sP[wv];
    #pragma unroll
    for (int jj = 0; jj < 4; jj++) {
      float cm = fmaxf(fmaxf(Sacc[0][jj] + mv[0], Sacc[1][jj] + mv[1]),
                       fmaxf(Sacc[2][jj] + mv[2], Sacc[3][jj] + mv[3]));
      #pragma unroll
      for (int d2 = 1; d2 < 16; d2 <<= 1) cm = fmaxf(cm, __shfl_xor(cm, d2, 64));
      float nm = fmaxf(mrun[jj], cm);
      float sc = __expf(mrun[jj] - nm);
      float rsum = 0.f; float pv[4];
      #pragma unroll
      for (int ni = 0; ni < 4; ni++) { pv[ni] = __expf(Sacc[ni][jj] + mv[ni] - nm); rsum += pv[ni]; }
      #pragma unroll
      for (int d2 = 1; d2 < 16; d2 <<= 1) rsum += __shfl_xor(rsum, d2, 64);
      mrun[jj] = nm; lrun[jj] = lrun[jj] * sc + rsum;
      #pragma unroll
      for (int di = 0; di < 4; di++) Oacc[di][jj] *= sc;
      int prow = hi * 4 + jj;
      #pragma unroll
      for (int ni = 0; ni < 4; ni++)
        *(bf16*)((char*)sPw + swz128(prow, ni * 16 + lo)) = (bf16)pv[ni];
    }
    #pragma unroll
    for (int kk = 0; kk < 2; kk++) {
      bf16x8 pF = *(const bf16x8*)((const char*)sPw + swz128(lo, kk * 32 + hi * 8));
      #pragma unroll
      for (int di = 0; di < 4; di++) {
        bf16x8 vF = *(const bf16x8*)((const char*)sV + swz128(di * 16 + lo, kk * 32 + hi * 8));
        Oacc[di] = __builtin_amdgcn_mfma_f32_16x16x32_bf16(pF, vF, Oacc[di], 0, 0, 0);
      }
    }
  }
  bf16* dst = attnRb + ((size_t)(n * RR + r)) * RS * 64;
  #pragma unroll
  for (int jj = 0; jj < 4; jj++) {
    float inv = 1.f / lrun[jj];
    int row = m0 + hi * 4 + jj;
    #pragma unroll
    for (int di = 0; di < 4; di++)
      dst[row * 64 + di * 16 + lo] = (bf16)(Oacc[di][jj] * inv);
  }
}

// ---------------- lepe 5x5 dw + from_regions (attnR bf16) ----------------
__global__ __launch_bounds__(256) void k_lepe2(const bf16* __restrict__ v_t, const bf16* __restrict__ attnRb,
    const float* __restrict__ lw, const float* __restrict__ lb, bf16* __restrict__ z_t) {
  __shared__ bf16 sH[400 * 72];
  __shared__ float sW[25][64];
  int r = blockIdx.x, n = blockIdx.y;
  int rh = (r / 7) * 16, rw = (r % 7) * 16;
  int tid = threadIdx.x;
  for (int i = tid; i < 1600; i += 256) { int c = i / 25, k = i % 25; sW[k][c] = lw[c * 25 + k]; }
  for (int g = tid; g < 3200; g += 256) {
    int pix = g >> 3, c4 = g & 7;
    int yy = pix / 20, xx = pix % 20;
    int hh = rh + yy - 2, ww = rw + xx - 2;
    uint4 d = {0, 0, 0, 0};
    if ((unsigned)hh < HW && (unsigned)ww < HW)
      d = *(const uint4*)(v_t + ((size_t)n * PP + hh * HW + ww) * 64 + c4 * 8);
    *(uint4*)((char*)sH + pix * 144 + c4 * 16) = d;
  }
  __syncthreads();
  int y = tid >> 4, x = tid & 15;
  float acc[64];
  const bf16* ar = attnRb + (((size_t)(n * RR + r)) * RS + tid) * 64;
  #pragma unroll
  for (int c8 = 0; c8 < 8; c8++) {
    bf16x8 av = *(const bf16x8*)(ar + c8 * 8);
    #pragma unroll
    for (int j = 0; j < 8; j++) acc[c8 * 8 + j] = lb[c8 * 8 + j] + (float)av[j];
  }
  for (int t25 = 0; t25 < 25; t25++) {
    int dh = t25 / 5, dw = t25 % 5;
    int pix = (y + dh) * 20 + (x + dw);
    #pragma unroll
    for (int c8 = 0; c8 < 8; c8++) {
      bf16x8 hv = *(const bf16x8*)((const char*)sH + pix * 144 + c8 * 16);
      #pragma unroll
      for (int j = 0; j < 8; j++) acc[c8 * 8 + j] += (float)hv[j] * sW[t25][c8 * 8 + j];
    }
  }
  bf16* zp = z_t + ((size_t)n * PP + (rh + y) * HW + rw + x) * 64;
  #pragma unroll
  for (int c8 = 0; c8 < 8; c8++) {
    bf16x8 o8;
    #pragma unroll
    for (int j = 0; j < 8; j++) o8[j] = (bf16)acc[c8 * 8 + j];
    *(bf16x8*)(zp + c8 * 8) = o8;
  }
}

// ---------------- proj GEMM: z_t -> x_t += ----------------
__global__ __launch_bounds__(256) void k_proj(const bf16* __restrict__ A, const float* __restrict__ w,
    const float* __restrict__ bias, float* __restrict__ xo) {
  __shared__ bf16 sA[128 * 64];
  __shared__ bf16 sB[64 * 64];
  int n = blockIdx.y;
  int p0 = blockIdx.x * 128;
  int tid = threadIdx.x, lane = tid & 63, wv = tid >> 6;
  int lo = lane & 15, hi = lane >> 4;
  const bf16* Abase = A + (size_t)n * PP * 64;
  #pragma unroll
  for (int it = 0; it < 4; it++) {
    int idx = tid + it * 256;
    int row = idx >> 3, c4 = idx & 7;
    uint4 d = *(const uint4*)(Abase + (size_t)(p0 + row) * 64 + c4 * 8);
    *(uint4*)((char*)sA + row * 128 + (((c4 ^ row) & 7) * 16)) = d;
  }
  #pragma unroll
  for (int it = 0; it < 4; it++) {
    int idx = tid + it * 256;
    int oo = idx >> 4, q = idx & 15;
    float4 wv4 = *(const float4*)&w[(size_t)oo * 64 + q * 4];
    bf16x4 b4; b4[0] = (bf16)wv4.x; b4[1] = (bf16)wv4.y; b4[2] = (bf16)wv4.z; b4[3] = (bf16)wv4.w;
    *(bf16x4*)((char*)sB + swz128(oo, q * 4)) = b4;
  }
  __syncthreads();
  f32x4 acc[2][4];
  #pragma unroll
  for (int mi = 0; mi < 2; mi++)
    #pragma unroll
    for (int ni = 0; ni < 4; ni++) acc[mi][ni] = (f32x4){0.f, 0.f, 0.f, 0.f};
  #pragma unroll
  for (int kk = 0; kk < 2; kk++) {
    bf16x8 aF[2], bF[4];
    #pragma unroll
    for (int mi = 0; mi < 2; mi++)
      aF[mi] = *(const bf16x8*)((const char*)sA + swz128(wv * 32 + mi * 16 + lo, kk * 32 + hi * 8));
    #pragma unroll
    for (int ni = 0; ni < 4; ni++)
      bF[ni] = *(const bf16x8*)((const char*)sB + swz128(ni * 16 + lo, kk * 32 + hi * 8));
    #pragma unroll
    for (int mi = 0; mi < 2; mi++)
      #pragma unroll
      for (int ni = 0; ni < 4; ni++)
        acc[mi][ni] = __builtin_amdgcn_mfma_f32_16x16x32_bf16(aF[mi], bF[ni], acc[mi][ni], 0, 0, 0);
  }
  #pragma unroll
  for (int ni = 0; ni < 4; ni++) {
    float bv = bias[ni * 16 + lo];
    #pragma unroll
    for (int mi = 0; mi < 2; mi++) {
      #pragma unroll
      for (int r2 = 0; r2 < 4; r2++) {
        int p = p0 + wv * 32 + mi * 16 + hi * 4 + r2;
        xo[((size_t)n * PP + p) * 64 + ni * 16 + lo] += acc[mi][ni][r2] + bv;
      }
    }
  }
}

// ---------------- fused MLP: LN2 + fc1 + gelu + fc2 + residual ----------------
__global__ __launch_bounds__(256) void k_mlp(const float* __restrict__ xin, const float* __restrict__ lng,
    const float* __restrict__ lnb, const float* __restrict__ w1, const float* __restrict__ b1,
    const float* __restrict__ w2, const float* __restrict__ b2, float* __restrict__ xo) {
  __shared__ bf16 sA[64 * 64];
  __shared__ bf16 sW1[128 * 64];
  __shared__ bf16 sHh[64 * 128];
  __shared__ bf16 sW2[64 * 128];
  int n = blockIdx.y;
  int p0 = blockIdx.x * 64;
  int tid = threadIdx.x, lane = tid & 63, wv = tid >> 6;
  int lo = lane & 15, hi = lane >> 4;
  { // fused LN staging: 4 threads per row, 16 channels each
    int row = tid >> 2, part = tid & 3;
    const float* xp = xin + ((size_t)n * PP + p0 + row) * 64 + part * 16;
    float v[16]; float s = 0.f, sq = 0.f;
    #pragma unroll
    for (int i = 0; i < 4; i++) {
      float4 d = *(const float4*)&xp[i * 4];
      v[i*4]=d.x; v[i*4+1]=d.y; v[i*4+2]=d.z; v[i*4+3]=d.w;
      s += d.x+d.y+d.z+d.w;
      sq += d.x*d.x+d.y*d.y+d.z*d.z+d.w*d.w;
    }
    s += __shfl_xor(s, 1, 64); sq += __shfl_xor(sq, 1, 64);
    s += __shfl_xor(s, 2, 64); sq += __shfl_xor(sq, 2, 64);
    float mu = s * (1.f/64.f);
    float rstd = rsqrtf(fmaxf(sq * (1.f/64.f) - mu*mu, 0.f) + 1e-5f);
    #pragma unroll
    for (int j2 = 0; j2 < 2; j2++) {
      bf16x8 o8;
      #pragma unroll
      for (int e = 0; e < 8; e++) {
        int c = part*16 + j2*8 + e;
        o8[e] = (bf16)((v[j2*8+e] - mu) * rstd * lng[c] + lnb[c]);
      }
      *(bf16x8*)((char*)sA + swz128(row, part*16 + j2*8)) = o8;
    }
  }
  f32x4 oacc[4];
  #pragma unroll
  for (int ni = 0; ni < 4; ni++) oacc[ni] = (f32x4){0.f, 0.f, 0.f, 0.f};
  for (int half = 0; half < 2; half++) {
    #pragma unroll
    for (int it = 0; it < 8; it++) {
      int idx = tid + it * 256;
      int oo = idx >> 4, q = idx & 15;
      float4 wv4 = *(const float4*)&w1[(size_t)(half * 128 + oo) * 64 + q * 4];
      bf16x4 b4; b4[0] = (bf16)wv4.x; b4[1] = (bf16)wv4.y; b4[2] = (bf16)wv4.z; b4[3] = (bf16)wv4.w;
      *(bf16x4*)((char*)sW1 + swz128(oo, q * 4)) = b4;
    }
    __syncthreads();
    f32x4 hacc[8];
    #pragma unroll
    for (int ni = 0; ni < 8; ni++) hacc[ni] = (f32x4){0.f, 0.f, 0.f, 0.f};
    #pragma unroll
    for (int kk = 0; kk < 2; kk++) {
      bf16x8 aF = *(const bf16x8*)((const char*)sA + swz128(wv * 16 + lo, kk * 32 + hi * 8));
      #pragma unroll
      for (int ni = 0; ni < 8; ni++) {
        bf16x8 bF = *(const bf16x8*)((const char*)sW1 + swz128(ni * 16 + lo, kk * 32 + hi * 8));
        hacc[ni] = __builtin_amdgcn_mfma_f32_16x16x32_bf16(aF, bF, hacc[ni], 0, 0, 0);
      }
    }
    #pragma unroll
    for (int ni = 0; ni < 8; ni++) {
      float bv = b1[half * 128 + ni * 16 + lo];
      #pragma unroll
      for (int r2 = 0; r2 < 4; r2++) {
        float hval = gelu_exact(hacc[ni][r2] + bv);
        *(bf16*)((char*)sHh + swzg(wv * 16 + hi * 4 + r2, ni * 16 + lo, 256)) = (bf16)hval;
      }
    }
    #pragma unroll
    for (int it = 0; it < 8; it++) {
      int idx = tid + it * 256;
      int oo = idx >> 5, q = idx & 31;
      float4 wv4 = *(const float4*)&w2[(size_t)oo * 256 + half * 128 + q * 4];
      bf16x4 b4; b4[0] = (bf16)wv4.x; b4[1] = (bf16)wv4.y; b4[2] = (bf16)wv4.z; b4[3] = (bf16)wv4.w;
      *(bf16x4*)((char*)sW2 + swzg(oo, q * 4, 256)) = b4;
    }
    __syncthreads();
    #pragma unroll
    for (int kk = 0; kk < 4; kk++) {
      bf16x8 aH = *(const bf16x8*)((const char*)sHh + swzg(wv * 16 + lo, kk * 32 + hi * 8, 256));
      #pragma unroll
      for (int ni = 0; ni < 4; ni++) {
        bf16x8 bF = *(const bf16x8*)((const char*)sW2 + swzg(ni * 16 + lo, kk * 32 + hi * 8, 256));
        oacc[ni] = __builtin_amdgcn_mfma_f32_16x16x32_bf16(aH, bF, oacc[ni], 0, 0, 0);
      }
    }
    __syncthreads();
  }
  #pragma unroll
  for (int ni = 0; ni < 4; ni++) {
    float bv = b2[ni * 16 + lo];
    #pragma unroll
    for (int r2 = 0; r2 < 4; r2++) {
      int p = p0 + wv * 16 + hi * 4 + r2;
      xo[((size_t)n * PP + p) * 64 + ni * 16 + lo] += oacc[ni][r2] + bv;
    }
  }
}

// ---------------- final untranspose: x_t[p][c] -> out[c][p] ----------------
__global__ __launch_bounds__(256) void k_untr(const float* __restrict__ x_t, float* __restrict__ out) {
  __shared__ float tile[64][68];
  int n = blockIdx.y; int p0 = blockIdx.x * 64;
  int tid = threadIdx.x;
  #pragma unroll
  for (int it = 0; it < 4; it++) {
    int g = tid + it * 256;
    int row = g >> 4, q = g & 15;
    float4 d = *(const float4*)&x_t[((size_t)n * PP + p0 + row) * 64 + q * 4];
    *(float4*)&tile[row][q * 4] = d;
  }
  __syncthreads();
  #pragma unroll
  for (int it = 0; it < 4; it++) {
    int g = tid + it * 256;
    int c = g >> 4, q = g & 15;
    float4 v;
    v.x = tile[q * 4 + 0][c]; v.y = tile[q * 4 + 1][c];
    v.z = tile[q * 4 + 2][c]; v.w = tile[q * 4 + 3][c];
    *(float4*)&out[((size_t)(n * 64 + c)) * PP + p0 + q * 4] = v;
  }
}

extern "C" void kernel_launch(void* const* d_in, const int* in_sizes, int n_in,
                              void* d_out, int out_size, void* d_ws, size_t ws_size,
                              hipStream_t stream) {
  const float* ex0 = (const float*)d_in[0];
  const float* ex  = (const float*)d_in[1];
  const float* img = (const float*)d_in[2];
  const float* pre = (const float*)d_in[3];
  const float* c0w = (const float*)d_in[4];
  const float* c0b = (const float*)d_in[5];
  const float* ln1g = (const float*)d_in[6];
  const float* ln1b = (const float*)d_in[7];
  const float* ln2g = (const float*)d_in[8];
  const float* ln2b = (const float*)d_in[9];
  const float* qkvw = (const float*)d_in[10];
  const float* qkvb = (const float*)d_in[11];
  const float* lw = (const float*)d_in[12];
  const float* lb = (const float*)d_in[13];
  const float* pw = (const float*)d_in[14];
  const float* pb = (const float*)d_in[15];
  const float* f1w = (const float*)d_in[16];
  const float* f1b = (const float*)d_in[17];
  const float* f2w = (const float*)d_in[18];
  const float* f2b = (const float*)d_in[19];

  float* W = (float*)d_ws;
  size_t o = 0;
  bf16* xct = (bf16*)(W + o);  o += (size_t)BB * GP * CK / 2;
  float* x_t  = W + o;         o += 3211264;
  bf16* attnRb = (bf16*)(W + o); o += 1605632;
  bf16* v_t  = (bf16*)(W + o); o += 1605632;
  bf16* z_t  = (bf16*)(W + o); o += 1605632;
  bf16* qR   = (bf16*)(W + o); o += 1605632;
  bf16* kR   = (bf16*)(W + o); o += 1605632;
  bf16* vT   = (bf16*)(W + o); o += 1605632;
  float* qd = W + o;           o += 12544;
  float* kd = W + o;           o += 12544;
  float* maskr = W + o;        o += 50176;
  bf16* wTb = (bf16*)(W + o);  o += 46080;
  int* gidx = (int*)(W + o);   o += 784;

  hipMemsetAsync(xct, 0, (size_t)BB * GP * CK * 2, stream);
  k_prep2<<<dim3(196, BB), dim3(256), 0, stream>>>(ex0, ex, img, pre, xct, maskr);
  k_wt2<<<dim3(360), dim3(256), 0, stream>>>(c0w, wTb);
  k_conv0m<<<dim3(98, BB), dim3(256), 0, stream>>>(xct, wTb, c0b, x_t);
  for (int i = 0; i < 4; i++) {
    k_qkv<<<dim3(98, BB), dim3(256), 0, stream>>>(x_t, ln1g + i * 64, ln1b + i * 64,
        qkvw + (size_t)i * 192 * 64, qkvb + i * 192, qR, kR, v_t);
    k_vpost<<<dim3(RR, BB), dim3(256), 0, stream>>>(qR, kR, v_t, qd, kd, vT);
    k_topk<<<dim3(RR, BB), dim3(64), 0, stream>>>(qd, kd, gidx);
    k_attn<<<dim3(BB * RR * 4), dim3(256), 0, stream>>>(qR, kR, vT, maskr, gidx, attnRb);
    k_lepe2<<<dim3(RR, BB), dim3(256), 0, stream>>>(v_t, attnRb, lw + (size_t)i * 64 * 25, lb + i * 64, z_t);
    k_proj<<<dim3(98, BB), dim3(256), 0, stream>>>(z_t, pw + (size_t)i * 64 * 64, pb + i * 64, x_t);
    k_mlp<<<dim3(196, BB), dim3(256), 0, stream>>>(x_t, ln2g + i * 64, ln2b + i * 64,
        f1w + (size_t)i * 256 * 64, f1b + i * 256, f2w + (size_t)i * 64 * 256, f2b + i * 64, x_t);
  }
  k_untr<<<dim3(196, BB), dim3(256), 0, stream>>>(x_t, (float*)d_out);
}